// Round 9
// baseline (429.878 us; speedup 1.0000x reference)
//
#include <hip/hip_runtime.h>
#include <hip/hip_bf16.h>
#include <stdint.h>

typedef unsigned short u16;
typedef __bf16 bf16x8 __attribute__((ext_vector_type(8)));
typedef float f32x4 __attribute__((ext_vector_type(4)));
typedef u16 u16x8 __attribute__((ext_vector_type(8)));
typedef u16 u16x4 __attribute__((ext_vector_type(4)));

__device__ __forceinline__ u16 f2bf(float f) {
  union { float f; uint32_t u; } v; v.f = f;
  uint32_t r = v.u + 0x7fffu + ((v.u >> 16) & 1u);
  return (u16)(r >> 16);
}
__device__ __forceinline__ float bf2f(u16 u) {
  union { uint32_t u; float f; } v; v.u = ((uint32_t)u) << 16;
  return v.f;
}
__device__ __forceinline__ uint32_t cvtpk(float a, float b) {
  uint32_t r;
  asm("v_cvt_pk_bf16_f32 %0, %1, %2" : "=v"(r) : "v"(a), "v"(b));
  return r;
}

// async global->LDS, 16B per lane. LDS dest must be linear (base + lane*16).
__device__ __forceinline__ void gld16(const u16* g, u16* l) {
  __builtin_amdgcn_global_load_lds(
      (const __attribute__((address_space(1))) uint32_t*)g,
      (__attribute__((address_space(3))) uint32_t*)l, 16, 0, 0);
}

// stage one 128x64 bf16 half-tile: 512 threads x 2 x 16B. LDS dest linear,
// global source pre-swizzled so reads use col16 ^ ((row&7)<<3).
__device__ __forceinline__ void stage_half(const u16* __restrict__ gbase, int ldg,
                                           u16* lbase, int tid) {
#pragma unroll
  for (int j = 0; j < 2; ++j) {
    const int idx = j * 512 + tid;
    const int row = idx >> 3, c8 = idx & 7;
    gld16(gbase + (size_t)row * ldg + ((c8 ^ (row & 7)) << 3), lbase + idx * 8);
  }
}

// ---------------- batched weight convert+transpose: W (K x N, f32) -> Wt (N x K, bf16)
struct WB {
  const float* src[6];
  u16* dst[6];
  float scale[6];
};
__global__ void wconv_b(WB wb, int K, int N) {
  const int z = blockIdx.z;
  const float* __restrict__ W = wb.src[z];
  u16* __restrict__ Wt = wb.dst[z];
  const float scale = wb.scale[z];
  __shared__ float tile[32][33];
  const int n0 = blockIdx.x * 32, k0 = blockIdx.y * 32;
  const int tx = threadIdx.x, ty = threadIdx.y;   // (32, 8)
#pragma unroll
  for (int i = 0; i < 4; ++i)
    tile[ty + 8 * i][tx] = W[(size_t)(k0 + ty + 8 * i) * N + n0 + tx];
  __syncthreads();
#pragma unroll
  for (int i = 0; i < 4; ++i)
    Wt[(size_t)(n0 + ty + 8 * i) * K + k0 + tx] = f2bf(scale * tile[tx][ty + 8 * i]);
}

// plain single-matrix variant (ff_w2)
__global__ void wconv_t(const float* __restrict__ W, u16* __restrict__ Wt, int K, int N) {
  __shared__ float tile[32][33];
  const int n0 = blockIdx.x * 32, k0 = blockIdx.y * 32;
  const int tx = threadIdx.x, ty = threadIdx.y;
#pragma unroll
  for (int i = 0; i < 4; ++i)
    tile[ty + 8 * i][tx] = W[(size_t)(k0 + ty + 8 * i) * N + n0 + tx];
  __syncthreads();
#pragma unroll
  for (int i = 0; i < 4; ++i)
    Wt[(size_t)(n0 + ty + 8 * i) * K + k0 + tx] = f2bf(tile[tx][ty + 8 * i]);
}

// ff_w1 convert with fragment-paired GEGLU rows:
// orig col n = half*4096 + blk*128 + wcol*32 + sub*16 + idx
// -> dst row p = blk*256 + wcol*64 + (sub*2+half)*16 + idx
__global__ void wconv_g(const float* __restrict__ W, u16* __restrict__ Wt) {
  __shared__ float tile[32][33];
  const int n0 = blockIdx.x * 32, k0 = blockIdx.y * 32;
  const int tx = threadIdx.x, ty = threadIdx.y;
#pragma unroll
  for (int i = 0; i < 4; ++i)
    tile[ty + 8 * i][tx] = W[(size_t)(k0 + ty + 8 * i) * 8192 + n0 + tx];
  __syncthreads();
#pragma unroll
  for (int i = 0; i < 4; ++i) {
    const int n = n0 + ty + 8 * i;
    const int half = n >> 12, c = n & 4095;
    const int blk = c >> 7, cc = c & 127;
    const int wcol = cc >> 5, rem = cc & 31;
    const int sub = rem >> 4, idx = rem & 15;
    const int p = blk * 256 + wcol * 64 + (sub * 2 + half) * 16 + idx;
    Wt[(size_t)p * 1024 + k0 + tx] = f2bf(tile[tx][ty + 8 * i]);
  }
}

// ---------------- simple f32 -> bf16 convert (encoder states)
__global__ void cvt_bf(const float* __restrict__ in, u16* __restrict__ out, int n) {
  int i = blockIdx.x * 256 + threadIdx.x;
  if (i < n) out[i] = f2bf(in[i]);
}

// ---------------- V transpose pre-pass: V rows (s) -> Vt[(bh*64+d)*S + t0*64 + pos(s)]
__global__ __launch_bounds__(256)
void vtrans(const u16* __restrict__ V, int ldv, int hoff, u16* __restrict__ Vt, int S) {
  __shared__ u16 tile[64][72];
  const int t0 = blockIdx.x, bh = blockIdx.y;
  const int b = bh >> 4, hc = (bh & 15) * 64 + hoff;
  const int tid = threadIdx.x;
  const int r = tid >> 2, dq = (tid & 3) * 16;
  const int pos = ((r >> 5) << 5) | (((r >> 2) & 3) << 3) | (((r >> 4) & 1) << 2) | (r & 3);
  const size_t grow = ((size_t)b * S + t0 * 64 + r) * ldv + hc + dq;
  u16x8 v1 = *(const u16x8*)&V[grow];
  u16x8 v2 = *(const u16x8*)&V[grow + 8];
#pragma unroll
  for (int j = 0; j < 8; ++j) {
    tile[dq + j][pos] = v1[j];
    tile[dq + 8 + j][pos] = v2[j];
  }
  __syncthreads();
  const int d = tid >> 2, c = (tid & 3) * 16;
  u16x8 o1, o2;
#pragma unroll
  for (int j = 0; j < 8; ++j) { o1[j] = tile[d][c + j]; o2[j] = tile[d][c + 8 + j]; }
  *(u16x8*)&Vt[((size_t)bh * 64 + d) * S + t0 * 64 + c] = o1;
  *(u16x8*)&Vt[((size_t)bh * 64 + d) * S + t0 * 64 + c + 8] = o2;
}

// ---------------- LayerNorm: row of 1024 f32 -> bf16
__global__ __launch_bounds__(256)
void ln_fwd(const float* __restrict__ X, const float* __restrict__ wt,
            const float* __restrict__ bs, u16* __restrict__ Y) {
  const int row = blockIdx.x, t = threadIdx.x;
  const float4 v = *(const float4*)&X[(size_t)row * 1024 + t * 4];
  float s = v.x + v.y + v.z + v.w;
  float s2 = v.x * v.x + v.y * v.y + v.z * v.z + v.w * v.w;
#pragma unroll
  for (int off = 32; off > 0; off >>= 1) {
    s += __shfl_xor(s, off);
    s2 += __shfl_xor(s2, off);
  }
  __shared__ float rs[4], rs2[4];
  const int w = t >> 6;
  if ((t & 63) == 0) { rs[w] = s; rs2[w] = s2; }
  __syncthreads();
  s = rs[0] + rs[1] + rs[2] + rs[3];
  s2 = rs2[0] + rs2[1] + rs2[2] + rs2[3];
  const float mu = s * (1.0f / 1024.0f);
  const float var = s2 * (1.0f / 1024.0f) - mu * mu;
  const float rstd = rsqrtf(var + 1e-5f);
  const float4 wv = *(const float4*)&wt[t * 4];
  const float4 bv = *(const float4*)&bs[t * 4];
  u16x4 o;
  o[0] = f2bf((v.x - mu) * rstd * wv.x + bv.x);
  o[1] = f2bf((v.y - mu) * rstd * wv.y + bv.y);
  o[2] = f2bf((v.z - mu) * rstd * wv.z + bv.z);
  o[3] = f2bf((v.w - mu) * rstd * wv.w + bv.w);
  *(u16x4*)&Y[(size_t)row * 1024 + t * 4] = o;
}

// ---------------- 128xTN 2-phase GEMM (N=1024-class shapes), XCD- + T2-swizzled
template<int TN>
__global__ __launch_bounds__(256, 4)
void gemm_bf16(const u16* __restrict__ A, int lda, const u16* __restrict__ Bt,
               int M, int N, int K, const float* __restrict__ bias,
               const float* __restrict__ resid, float oscale,
               float* __restrict__ outF, u16* __restrict__ outB) {
  constexpr int WNV = (TN == 128) ? 2 : 1;
  constexpr int WMV = 4 / WNV;
  constexpr int WM = 128 / WMV;
  constexpr int WN = TN / WNV;
  constexpr int MI = WM / 16, NI = WN / 16;
  __shared__ __align__(16) u16 Al[128 * 64];
  __shared__ __align__(16) u16 Bl[TN * 64];
  const int tid = threadIdx.x;
  const int w = tid >> 6, l = tid & 63, lo = l & 15, g = l >> 4;
  const int gx = gridDim.x, nwg = gx * gridDim.y;
  const int lin = blockIdx.y * gx + blockIdx.x;
  const int q = nwg >> 3, r = nwg & 7;
  const int xcd = lin & 7, pos = lin >> 3;
  const int sid = (xcd < r ? xcd * (q + 1) : r * (q + 1) + (xcd - r) * q) + pos;
  const int bm = (sid % gx) * 128, bn = (sid / gx) * TN;
  const int wm = (w / WNV) * WM, wn = (w % WNV) * WN;
  const int swz = (lo & 7) << 3;
  f32x4 acc[MI][NI] = {};

  for (int k0 = 0; k0 < K; k0 += 64) {
#pragma unroll
    for (int p = 0; p < 4; ++p) {
      int idx = p * 256 + tid;
      int row = idx >> 3, c = idx & 7;
      gld16(A + (size_t)(bm + row) * lda + k0 + ((c ^ (row & 7)) << 3), &Al[idx * 8]);
    }
#pragma unroll
    for (int p = 0; p < TN / 32; ++p) {
      int idx = p * 256 + tid;
      int row = idx >> 3, c = idx & 7;
      gld16(Bt + (size_t)(bn + row) * K + k0 + ((c ^ (row & 7)) << 3), &Bl[idx * 8]);
    }
    asm volatile("s_waitcnt vmcnt(0)" ::: "memory");
    __syncthreads();
#pragma unroll
    for (int ks = 0; ks < 2; ++ks) {
      bf16x8 af[MI], bf[NI];
#pragma unroll
      for (int i = 0; i < MI; ++i)
        af[i] = *(const bf16x8*)&Al[(wm + i * 16 + lo) * 64 + ((ks * 32 + g * 8) ^ swz)];
#pragma unroll
      for (int i = 0; i < NI; ++i)
        bf[i] = *(const bf16x8*)&Bl[(wn + i * 16 + lo) * 64 + ((ks * 32 + g * 8) ^ swz)];
#pragma unroll
      for (int mi = 0; mi < MI; ++mi)
#pragma unroll
        for (int ni = 0; ni < NI; ++ni)
          acc[mi][ni] = __builtin_amdgcn_mfma_f32_16x16x32_bf16(af[mi], bf[ni], acc[mi][ni], 0, 0, 0);
    }
    __syncthreads();
  }

#pragma unroll
  for (int mi = 0; mi < MI; ++mi) {
#pragma unroll
    for (int ni = 0; ni < NI; ++ni) {
      const int col = bn + wn + ni * 16 + lo;
      const float bb = bias ? bias[col] : 0.0f;
      const int row0 = bm + wm + mi * 16 + g * 4;
#pragma unroll
      for (int rr = 0; rr < 4; ++rr) {
        const size_t off = (size_t)(row0 + rr) * N + col;
        float v = acc[mi][ni][rr] * oscale + bb;
        if (resid) v += resid[off];
        if (outF) outF[off] = v;
        else outB[off] = f2bf(v);
      }
    }
  }
}

// ---------------- 256x256 8-phase GEMM; balanced ds_reads, compiler-counted lgkm
// MODE 0: normal epilogue. MODE 1: register-paired GEGLU epilogue:
// acc[mi][2s] = h1, acc[mi][2s+1] = h2 for the SAME output col; out = h1*gelu(h2).
template<int MODE>
__global__ __launch_bounds__(512, 2)
void gemm256(const u16* __restrict__ A, int lda, const u16* __restrict__ Bt,
             int M, int N, int K, const float* __restrict__ bias,
             const float* __restrict__ resid, float oscale,
             float* __restrict__ outF, u16* __restrict__ outB) {
  __shared__ __align__(16) u16 sm[65536];   // [2 dbuf][A 16384 | B 16384] u16
  const int tid = threadIdx.x;
  const int w = tid >> 6, l = tid & 63, lo = l & 15, g = l >> 4;
  const int wrow = w >> 2, wcol = w & 3;
  const int gx = gridDim.x;
  const int nwg = gx * gridDim.y;
  const int lin = blockIdx.y * gx + blockIdx.x;
  const int q = nwg >> 3, r = nwg & 7;
  const int xcd = lin & 7, pos = lin >> 3;
  const int sid = (xcd < r ? xcd * (q + 1) : r * (q + 1) + (xcd - r) * q) + pos;
  const int bm = (sid % gx) * 256, bn = (sid / gx) * 256;

  const int NT = K >> 6;
  const int swz = (lo & 7) << 3;
  f32x4 acc[8][4] = {};

  stage_half(Bt + (size_t)bn * K, K, sm + 16384, tid);
  stage_half(Bt + (size_t)(bn + 128) * K, K, sm + 16384 + 8192, tid);
  stage_half(A + (size_t)bm * lda, lda, sm, tid);
  stage_half(A + (size_t)(bm + 128) * lda, lda, sm + 8192, tid);
  if (NT > 1) {
    stage_half(Bt + (size_t)bn * K + 64, K, sm + 32768 + 16384, tid);
    stage_half(Bt + (size_t)(bn + 128) * K + 64, K, sm + 32768 + 16384 + 8192, tid);
    stage_half(A + (size_t)bm * lda + 64, lda, sm + 32768, tid);
  }
  asm volatile("s_waitcnt vmcnt(6)" ::: "memory");
  __builtin_amdgcn_s_barrier();

  for (int t = 0; t < NT; ++t) {
    u16* Ab_ = sm + (t & 1) * 32768;
    u16* Bb_ = Ab_ + 16384;
    bf16x8 a0[4][2], a1[4][2], bfr[4][2];
    // ---- phase 0: read a0 + all B; stage A.h1(t+1); MFMA (m0,n01)
#pragma unroll
    for (int mf = 0; mf < 4; ++mf) {
      const int rowi = wrow * 128 + mf * 16 + lo;
#pragma unroll
      for (int kk = 0; kk < 2; ++kk)
        a0[mf][kk] = *(const bf16x8*)&Ab_[rowi * 64 + ((kk * 32 + g * 8) ^ swz)];
    }
#pragma unroll
    for (int nf = 0; nf < 4; ++nf) {
      const int rowi = wcol * 64 + nf * 16 + lo;
#pragma unroll
      for (int kk = 0; kk < 2; ++kk)
        bfr[nf][kk] = *(const bf16x8*)&Bb_[rowi * 64 + ((kk * 32 + g * 8) ^ swz)];
    }
    if (t + 1 < NT)
      stage_half(A + (size_t)(bm + 128) * lda + (t + 1) * 64, lda,
                 sm + ((t + 1) & 1) * 32768 + 8192, tid);
    __builtin_amdgcn_s_barrier();
    __builtin_amdgcn_s_setprio(1);
#pragma unroll
    for (int mf = 0; mf < 4; ++mf)
#pragma unroll
      for (int nf = 0; nf < 2; ++nf)
#pragma unroll
        for (int kk = 0; kk < 2; ++kk)
          acc[mf][nf] = __builtin_amdgcn_mfma_f32_16x16x32_bf16(a0[mf][kk], bfr[nf][kk], acc[mf][nf], 0, 0, 0);
    __builtin_amdgcn_s_setprio(0);
    __builtin_amdgcn_s_barrier();
    // ---- phase 1: read a1; stage B.h0(t+2); MFMA (m0,n23)
#pragma unroll
    for (int mf = 0; mf < 4; ++mf) {
      const int rowi = wrow * 128 + 64 + mf * 16 + lo;
#pragma unroll
      for (int kk = 0; kk < 2; ++kk)
        a1[mf][kk] = *(const bf16x8*)&Ab_[rowi * 64 + ((kk * 32 + g * 8) ^ swz)];
    }
    if (t + 2 < NT)
      stage_half(Bt + (size_t)bn * K + (t + 2) * 64, K,
                 sm + (t & 1) * 32768 + 16384, tid);
    __builtin_amdgcn_s_barrier();
    __builtin_amdgcn_s_setprio(1);
#pragma unroll
    for (int mf = 0; mf < 4; ++mf)
#pragma unroll
      for (int nf = 2; nf < 4; ++nf)
#pragma unroll
        for (int kk = 0; kk < 2; ++kk)
          acc[mf][nf] = __builtin_amdgcn_mfma_f32_16x16x32_bf16(a0[mf][kk], bfr[nf][kk], acc[mf][nf], 0, 0, 0);
    __builtin_amdgcn_s_setprio(0);
    __builtin_amdgcn_s_barrier();
    // ---- phase 2: stage B.h1(t+2); MFMA (m1,n01)
    if (t + 2 < NT)
      stage_half(Bt + (size_t)(bn + 128) * K + (t + 2) * 64, K,
                 sm + (t & 1) * 32768 + 16384 + 8192, tid);
    __builtin_amdgcn_s_barrier();
    __builtin_amdgcn_s_setprio(1);
#pragma unroll
    for (int mf = 0; mf < 4; ++mf)
#pragma unroll
      for (int nf = 0; nf < 2; ++nf)
#pragma unroll
        for (int kk = 0; kk < 2; ++kk)
          acc[4 + mf][nf] = __builtin_amdgcn_mfma_f32_16x16x32_bf16(a1[mf][kk], bfr[nf][kk], acc[4 + mf][nf], 0, 0, 0);
    __builtin_amdgcn_s_setprio(0);
    __builtin_amdgcn_s_barrier();
    // ---- phase 3: stage A.h0(t+2); MFMA (m1,n23); counted vmcnt (0 at tail)
    if (t + 2 < NT)
      stage_half(A + (size_t)bm * lda + (t + 2) * 64, lda,
                 sm + (t & 1) * 32768, tid);
    __builtin_amdgcn_s_barrier();
    __builtin_amdgcn_s_setprio(1);
#pragma unroll
    for (int mf = 0; mf < 4; ++mf)
#pragma unroll
      for (int nf = 2; nf < 4; ++nf)
#pragma unroll
        for (int kk = 0; kk < 2; ++kk)
          acc[4 + mf][nf] = __builtin_amdgcn_mfma_f32_16x16x32_bf16(a1[mf][kk], bfr[nf][kk], acc[4 + mf][nf], 0, 0, 0);
    __builtin_amdgcn_s_setprio(0);
    if (t + 2 < NT) asm volatile("s_waitcnt vmcnt(6)" ::: "memory");
    else            asm volatile("s_waitcnt vmcnt(0)" ::: "memory");
    __builtin_amdgcn_s_barrier();
  }

  if (MODE == 1) {
    // register-paired GEGLU: acc[mi][2s]=h1, acc[mi][2s+1]=h2, same out col.
    const int obase = bn >> 1;
#pragma unroll
    for (int mi = 0; mi < 8; ++mi) {
#pragma unroll
      for (int sub = 0; sub < 2; ++sub) {
        const int col = obase + wcol * 32 + sub * 16 + lo;
        const float b1 = bias[col];
        const float b2 = bias[4096 + col];
#pragma unroll
        for (int rr = 0; rr < 4; ++rr) {
          const int rowi = wrow * 128 + mi * 16 + g * 4 + rr;
          const float h1 = acc[mi][sub * 2][rr] + b1;
          const float h2 = acc[mi][sub * 2 + 1][rr] + b2;
          const float ge = 0.5f * h2 * (1.0f + erff(h2 * 0.70710678118f));
          outB[(size_t)(bm + rowi) * 4096 + col] = f2bf(h1 * ge);
        }
      }
    }
    return;
  }

#pragma unroll
  for (int mi = 0; mi < 8; ++mi) {
#pragma unroll
    for (int ni = 0; ni < 4; ++ni) {
      const int col = bn + wcol * 64 + ni * 16 + lo;
      const float bb = bias ? bias[col] : 0.0f;
      const int row0 = bm + wrow * 128 + mi * 16 + g * 4;
#pragma unroll
      for (int rr = 0; rr < 4; ++rr) {
        const size_t off = (size_t)(row0 + rr) * N + col;
        float v = acc[mi][ni][rr] * oscale + bb;
        if (resid) v += resid[off];
        if (outF) outF[off] = v;
        else outB[off] = f2bf(v);
      }
    }
  }
}

// ---------------- fused flash attention v4: QK one-tile-ahead pipeline.
// iter t: stage K(t+2)->Kl[t&1], V(t+1)->Vl[(t+1)&1]; QK(t+1) MFMAs issue
// BEFORE softmax(t) VALU (separate pipes overlap); PV(t) after.
__global__ __launch_bounds__(256, 4)
void attn_fwd(const u16* __restrict__ Q, int ldq, const u16* __restrict__ K, int ldk,
              const u16* __restrict__ Vt, u16* __restrict__ O, int T, int S) {
  __shared__ __align__(16) u16 Kl[2][4096];
  __shared__ __align__(16) u16 Vl[2][4096];
  const int tid = threadIdx.x, w = tid >> 6, l = tid & 63, lo = l & 15, g = l >> 4;
  const int nwg = gridDim.x * gridDim.y;
  const int n = blockIdx.y * gridDim.x + blockIdx.x;
  const int sid = (n & 7) * (nwg >> 3) + (n >> 3);
  const int qt = sid % gridDim.x, bh = sid / gridDim.x;
  const int b = bh >> 4, h = bh & 15, hc = h * 64;
  const int q0 = qt * 64 + w * 16;
  const size_t qrow = (size_t)b * T + q0;
  const size_t krow0 = (size_t)b * S;
  const size_t vrow0 = (size_t)bh * 64;

  bf16x8 qf[2];
#pragma unroll
  for (int kk = 0; kk < 2; ++kk)
    qf[kk] = *(const bf16x8*)&Q[(qrow + lo) * ldq + hc + kk * 32 + g * 8];

  f32x4 oa[4] = {};
  float m = -1e30f, lsum = 0.0f;

  const int srow = tid >> 3;
  const int scol = (((tid & 7) ^ (srow & 7)) << 3);
  const int ntile = S >> 6;

  // prologue: K(0)->Kl[0], K(1)->Kl[1], V(0)->Vl[0]; then QK(0)->sC
#pragma unroll
  for (int c = 0; c < 2; ++c)
    gld16(K + (krow0 + c * 32 + srow) * ldk + hc + scol, &Kl[0][c * 2048 + tid * 8]);
#pragma unroll
  for (int c = 0; c < 2; ++c)
    gld16(K + (krow0 + 64 + c * 32 + srow) * ldk + hc + scol, &Kl[1][c * 2048 + tid * 8]);
#pragma unroll
  for (int c = 0; c < 2; ++c)
    gld16(Vt + (vrow0 + c * 32 + srow) * S + scol, &Vl[0][c * 2048 + tid * 8]);
  asm volatile("s_waitcnt vmcnt(0)" ::: "memory");
  __builtin_amdgcn_s_barrier();

  f32x4 sC[4] = {};
#pragma unroll
  for (int c = 0; c < 4; ++c)
#pragma unroll
    for (int kk = 0; kk < 2; ++kk) {
      bf16x8 kf = *(const bf16x8*)&Kl[0][(c * 16 + lo) * 64 +
                                        ((kk * 32 + g * 8) ^ ((lo & 7) << 3))];
      sC[c] = __builtin_amdgcn_mfma_f32_16x16x32_bf16(kf, qf[kk], sC[c], 0, 0, 0);
    }
  asm volatile("s_waitcnt lgkmcnt(0)" ::: "memory");
  __builtin_amdgcn_s_barrier();

  for (int t0 = 0; t0 < ntile; ++t0) {
    const int cur = t0 & 1, nxt = cur ^ 1;
    // stage K(t+2) -> Kl[cur], V(t+1) -> Vl[nxt]
    if (t0 + 2 < ntile) {
#pragma unroll
      for (int c = 0; c < 2; ++c)
        gld16(K + (krow0 + (t0 + 2) * 64 + c * 32 + srow) * ldk + hc + scol,
              &Kl[cur][c * 2048 + tid * 8]);
    }
    if (t0 + 1 < ntile) {
#pragma unroll
      for (int c = 0; c < 2; ++c)
        gld16(Vt + (vrow0 + c * 32 + srow) * S + (t0 + 1) * 64 + scol,
              &Vl[nxt][c * 2048 + tid * 8]);
    }
    if (t0 + 2 < ntile)      asm volatile("s_waitcnt vmcnt(4)" ::: "memory");
    else if (t0 + 1 < ntile) asm volatile("s_waitcnt vmcnt(2)" ::: "memory");
    else                     asm volatile("s_waitcnt vmcnt(0)" ::: "memory");
    __builtin_amdgcn_s_barrier();

    // QK(t+1) issue first (fills MFMA pipe under softmax VALU)
    f32x4 sN[4] = {};
    if (t0 + 1 < ntile) {
#pragma unroll
      for (int c = 0; c < 4; ++c)
#pragma unroll
        for (int kk = 0; kk < 2; ++kk) {
          bf16x8 kf = *(const bf16x8*)&Kl[nxt][(c * 16 + lo) * 64 +
                                              ((kk * 32 + g * 8) ^ ((lo & 7) << 3))];
          sN[c] = __builtin_amdgcn_mfma_f32_16x16x32_bf16(kf, qf[kk], sN[c], 0, 0, 0);
        }
    }

    // online softmax on sC (tile t0), base-2
    float mx = fmaxf(fmaxf(fmaxf(sC[0][0], sC[0][1]), fmaxf(sC[0][2], sC[0][3])),
                     fmaxf(fmaxf(sC[1][0], sC[1][1]), fmaxf(sC[1][2], sC[1][3])));
    mx = fmaxf(mx, fmaxf(fmaxf(fmaxf(sC[2][0], sC[2][1]), fmaxf(sC[2][2], sC[2][3])),
                         fmaxf(fmaxf(sC[3][0], sC[3][1]), fmaxf(sC[3][2], sC[3][3]))));
    mx = fmaxf(mx, __shfl_xor(mx, 16));
    mx = fmaxf(mx, __shfl_xor(mx, 32));
    const float mn = fmaxf(m, mx);
    const float al = exp2f(m - mn);
    m = mn;
    float psum = 0.0f;
#pragma unroll
    for (int c = 0; c < 4; ++c)
#pragma unroll
      for (int rr = 0; rr < 4; ++rr) {
        sC[c][rr] = exp2f(sC[c][rr] - mn);
        psum += sC[c][rr];
      }
    psum += __shfl_xor(psum, 16);
    psum += __shfl_xor(psum, 32);
    lsum = lsum * al + psum;
    f32x4 arv;
#pragma unroll
    for (int rr = 0; rr < 4; ++rr) arv[rr] = __shfl(al, 20 * g + rr);
#pragma unroll
    for (int dn = 0; dn < 4; ++dn) oa[dn] *= arv;

    union { uint32_t u[4]; bf16x8 v; } af[2];
#pragma unroll
    for (int ks = 0; ks < 2; ++ks) {
      af[ks].u[0] = cvtpk(sC[2 * ks][0], sC[2 * ks][1]);
      af[ks].u[1] = cvtpk(sC[2 * ks][2], sC[2 * ks][3]);
      af[ks].u[2] = cvtpk(sC[2 * ks + 1][0], sC[2 * ks + 1][1]);
      af[ks].u[3] = cvtpk(sC[2 * ks + 1][2], sC[2 * ks + 1][3]);
    }
    // PV(t0) from Vl[cur]
#pragma unroll
    for (int dn = 0; dn < 4; ++dn)
#pragma unroll
      for (int ks = 0; ks < 2; ++ks) {
        bf16x8 vf = *(const bf16x8*)&Vl[cur][(dn * 16 + lo) * 64 +
                                            ((ks * 32 + g * 8) ^ ((lo & 7) << 3))];
        oa[dn] = __builtin_amdgcn_mfma_f32_16x16x32_bf16(af[ks].v, vf, oa[dn], 0, 0, 0);
      }
    asm volatile("s_waitcnt lgkmcnt(0)" ::: "memory");
    __builtin_amdgcn_s_barrier();
#pragma unroll
    for (int c = 0; c < 4; ++c) sC[c] = sN[c];
  }

  const float il = 1.0f / lsum;
  float ir[4];
#pragma unroll
  for (int rr = 0; rr < 4; ++rr) ir[rr] = __shfl(il, 20 * g + rr);
#pragma unroll
  for (int dn = 0; dn < 4; ++dn)
#pragma unroll
    for (int rr = 0; rr < 4; ++rr)
      O[(qrow + g * 4 + rr) * 1024 + hc + dn * 16 + lo] = f2bf(oa[dn][rr] * ir[rr]);
}

extern "C" void kernel_launch(void* const* d_in, const int* in_sizes, int n_in,
                              void* d_out, int out_size, void* d_ws, size_t ws_size,
                              hipStream_t stream) {
  const float* x      = (const float*)d_in[0];
  const float* enc    = (const float*)d_in[1];
  const float* ln1_w  = (const float*)d_in[2];
  const float* ln1_b  = (const float*)d_in[3];
  const float* a1_wq  = (const float*)d_in[4];
  const float* a1_wk  = (const float*)d_in[5];
  const float* a1_wv  = (const float*)d_in[6];
  const float* a1_wo  = (const float*)d_in[7];
  const float* a1_bo  = (const float*)d_in[8];
  const float* ln2_w  = (const float*)d_in[9];
  const float* ln2_b  = (const float*)d_in[10];
  const float* a2_wq  = (const float*)d_in[11];
  const float* a2_wk  = (const float*)d_in[12];
  const float* a2_wv  = (const float*)d_in[13];
  const float* a2_wo  = (const float*)d_in[14];
  const float* a2_bo  = (const float*)d_in[15];
  const float* ln3_w  = (const float*)d_in[16];
  const float* ln3_b  = (const float*)d_in[17];
  const float* ff_w1  = (const float*)d_in[18];
  const float* ff_b1  = (const float*)d_in[19];
  const float* ff_w2  = (const float*)d_in[20];
  const float* ff_b2  = (const float*)d_in[21];

  char* ws = (char*)d_ws;
  const size_t MB = 1u << 20;
  u16* wqkv1t = (u16*)(ws + 0 * MB);              // 3072x1024 = 6 MB
  u16* wo1t   = (u16*)(ws + 6 * MB);
  u16* wq2t   = (u16*)(ws + 8 * MB);
  u16* wo2t   = (u16*)(ws + 10 * MB);
  u16* wkv2t  = (u16*)(ws + 12 * MB);             // 2048x64 = 256 KB
  u16* encb   = (u16*)(ws + 12 * MB + 512 * 1024);
  u16* w1t    = (u16*)(ws + 13 * MB);             // 16 MB (geglu-paired)
  u16* w2t    = (u16*)(ws + 29 * MB);             // 8 MB
  float* x2   = (float*)(ws + 37 * MB);           // 16 MB (live from wo2 on)
  u16* Vt1    = (u16*)(ws + 37 * MB);             // 8 MB (dead before wo2)
  u16* Vt2    = (u16*)(ws + 45 * MB);             // 2 MB (dead before wo2)
  u16* KVb    = (u16*)(ws + 47 * MB);             // 1024x2048 = 4 MB
  u16* hbuf   = (u16*)(ws + 53 * MB);             // 8 MB
  u16* qkv    = (u16*)(ws + 61 * MB);             // 24 MB
  u16* Qb     = (u16*)(ws + 61 * MB);             // cross-attn reuse
  u16* Ab     = (u16*)(ws + 85 * MB);             // 8 MB
  float* x1   = (float*)(ws + 93 * MB);           // 16 MB -> 109
  u16* gq     = (u16*)(ws + 61 * MB);             // 4096x4096 = 32 MB (reuses qkv/Ab)

  const float SCL = 0.125f * 1.44269504f;
  const dim3 tb(32, 8);
  {
    WB wb;
    wb.src[0] = a1_wq; wb.dst[0] = wqkv1t;               wb.scale[0] = SCL;
    wb.src[1] = a1_wk; wb.dst[1] = wqkv1t + 1024 * 1024; wb.scale[1] = 1.0f;
    wb.src[2] = a1_wv; wb.dst[2] = wqkv1t + 2048 * 1024; wb.scale[2] = 1.0f;
    wb.src[3] = a1_wo; wb.dst[3] = wo1t;                 wb.scale[3] = 1.0f;
    wb.src[4] = a2_wq; wb.dst[4] = wq2t;                 wb.scale[4] = SCL;
    wb.src[5] = a2_wo; wb.dst[5] = wo2t;                 wb.scale[5] = 1.0f;
    wconv_b<<<dim3(32, 32, 6), tb, 0, stream>>>(wb, 1024, 1024);
    WB wb2;
    wb2.src[0] = a2_wk; wb2.dst[0] = wkv2t;             wb2.scale[0] = 1.0f;
    wb2.src[1] = a2_wv; wb2.dst[1] = wkv2t + 64 * 1024; wb2.scale[1] = 1.0f;
    wb2.src[2] = a2_wk; wb2.dst[2] = wkv2t;             wb2.scale[2] = 1.0f;
    wb2.src[3] = a2_wk; wb2.dst[3] = wkv2t;             wb2.scale[3] = 1.0f;
    wb2.src[4] = a2_wk; wb2.dst[4] = wkv2t;             wb2.scale[4] = 1.0f;
    wb2.src[5] = a2_wk; wb2.dst[5] = wkv2t;             wb2.scale[5] = 1.0f;
    wconv_b<<<dim3(32, 2, 2), tb, 0, stream>>>(wb2, 64, 1024);
  }
  wconv_g<<<dim3(256, 32), tb, 0, stream>>>(ff_w1, w1t);
  wconv_t<<<dim3(32, 128), tb, 0, stream>>>(ff_w2, w2t, 4096, 1024);
  cvt_bf<<<256, 256, 0, stream>>>(enc, encb, 2 * 512 * 64);

  // ---- self-attention sub-block
  ln_fwd<<<4096, 256, 0, stream>>>(x, ln1_w, ln1_b, hbuf);
  gemm256<0><<<dim3(16, 12), 512, 0, stream>>>(hbuf, 1024, wqkv1t, 4096, 3072, 1024, nullptr, nullptr, 1.0f, nullptr, qkv);
  vtrans<<<dim3(32, 32), 256, 0, stream>>>(qkv, 3072, 2048, Vt1, 2048);
  attn_fwd<<<dim3(32, 32), 256, 0, stream>>>(qkv, 3072, qkv + 1024, 3072, Vt1, Ab, 2048, 2048);
  gemm_bf16<64><<<dim3(32, 16), 256, 0, stream>>>(Ab, 1024, wo1t, 4096, 1024, 1024, a1_bo, x, 1.0f, x1, nullptr);

  // ---- cross-attention sub-block
  ln_fwd<<<4096, 256, 0, stream>>>(x1, ln2_w, ln2_b, hbuf);
  gemm_bf16<64><<<dim3(32, 16), 256, 0, stream>>>(hbuf, 1024, wq2t, 4096, 1024, 1024, nullptr, nullptr, 1.0f, nullptr, Qb);
  gemm_bf16<64><<<dim3(8, 32), 256, 0, stream>>>(encb, 64, wkv2t, 1024, 2048, 64, nullptr, nullptr, 1.0f, nullptr, KVb);
  vtrans<<<dim3(8, 32), 256, 0, stream>>>(KVb + 1024, 2048, 0, Vt2, 512);
  attn_fwd<<<dim3(32, 32), 256, 0, stream>>>(Qb, 1024, KVb, 2048, Vt2, Ab, 2048, 512);
  gemm_bf16<64><<<dim3(32, 16), 256, 0, stream>>>(Ab, 1024, wo2t, 4096, 1024, 1024, a2_bo, x1, 1.0f, x2, nullptr);

  // ---- GEGLU feed-forward sub-block (geglu fused into FF1 epilogue)
  ln_fwd<<<4096, 256, 0, stream>>>(x2, ln3_w, ln3_b, hbuf);
  gemm256<1><<<dim3(16, 32), 512, 0, stream>>>(hbuf, 1024, w1t, 4096, 8192, 1024, ff_b1, nullptr, 1.0f, nullptr, gq);
  gemm_bf16<64><<<dim3(32, 16), 256, 0, stream>>>(gq, 4096, w2t, 4096, 1024, 4096, ff_b2, x2, 1.0f, (float*)d_out, nullptr);
}

// Round 10
// 417.980 us; speedup vs baseline: 1.0285x; 1.0285x over previous
//
#include <hip/hip_runtime.h>
#include <hip/hip_bf16.h>
#include <stdint.h>

typedef unsigned short u16;
typedef __bf16 bf16x8 __attribute__((ext_vector_type(8)));
typedef float f32x4 __attribute__((ext_vector_type(4)));
typedef u16 u16x8 __attribute__((ext_vector_type(8)));
typedef u16 u16x4 __attribute__((ext_vector_type(4)));

__device__ __forceinline__ u16 f2bf(float f) {
  union { float f; uint32_t u; } v; v.f = f;
  uint32_t r = v.u + 0x7fffu + ((v.u >> 16) & 1u);
  return (u16)(r >> 16);
}
__device__ __forceinline__ float bf2f(u16 u) {
  union { uint32_t u; float f; } v; v.u = ((uint32_t)u) << 16;
  return v.f;
}
__device__ __forceinline__ uint32_t cvtpk(float a, float b) {
  uint32_t r;
  asm("v_cvt_pk_bf16_f32 %0, %1, %2" : "=v"(r) : "v"(a), "v"(b));
  return r;
}

// async global->LDS, 16B per lane. LDS dest must be linear (base + lane*16).
__device__ __forceinline__ void gld16(const u16* g, u16* l) {
  __builtin_amdgcn_global_load_lds(
      (const __attribute__((address_space(1))) uint32_t*)g,
      (__attribute__((address_space(3))) uint32_t*)l, 16, 0, 0);
}

// stage one 128x64 bf16 half-tile: 512 threads x 2 x 16B. LDS dest linear,
// global source pre-swizzled so reads use col16 ^ ((row&7)<<3).
__device__ __forceinline__ void stage_half(const u16* __restrict__ gbase, int ldg,
                                           u16* lbase, int tid) {
#pragma unroll
  for (int j = 0; j < 2; ++j) {
    const int idx = j * 512 + tid;
    const int row = idx >> 3, c8 = idx & 7;
    gld16(gbase + (size_t)row * ldg + ((c8 ^ (row & 7)) << 3), lbase + idx * 8);
  }
}

// ---------------- batched weight convert+transpose: W (K x N, f32) -> Wt (N x K, bf16)
struct WB {
  const float* src[6];
  u16* dst[6];
  float scale[6];
};
__global__ void wconv_b(WB wb, int K, int N) {
  const int z = blockIdx.z;
  const float* __restrict__ W = wb.src[z];
  u16* __restrict__ Wt = wb.dst[z];
  const float scale = wb.scale[z];
  __shared__ float tile[32][33];
  const int n0 = blockIdx.x * 32, k0 = blockIdx.y * 32;
  const int tx = threadIdx.x, ty = threadIdx.y;   // (32, 8)
#pragma unroll
  for (int i = 0; i < 4; ++i)
    tile[ty + 8 * i][tx] = W[(size_t)(k0 + ty + 8 * i) * N + n0 + tx];
  __syncthreads();
#pragma unroll
  for (int i = 0; i < 4; ++i)
    Wt[(size_t)(n0 + ty + 8 * i) * K + k0 + tx] = f2bf(scale * tile[tx][ty + 8 * i]);
}

// plain single-matrix variant (ff_w2)
__global__ void wconv_t(const float* __restrict__ W, u16* __restrict__ Wt, int K, int N) {
  __shared__ float tile[32][33];
  const int n0 = blockIdx.x * 32, k0 = blockIdx.y * 32;
  const int tx = threadIdx.x, ty = threadIdx.y;
#pragma unroll
  for (int i = 0; i < 4; ++i)
    tile[ty + 8 * i][tx] = W[(size_t)(k0 + ty + 8 * i) * N + n0 + tx];
  __syncthreads();
#pragma unroll
  for (int i = 0; i < 4; ++i)
    Wt[(size_t)(n0 + ty + 8 * i) * K + k0 + tx] = f2bf(tile[tx][ty + 8 * i]);
}

// ff_w1 convert with fragment-paired GEGLU rows:
// orig col n = half*4096 + blk*128 + wcol*32 + sub*16 + idx
// -> dst row p = blk*256 + wcol*64 + (sub*2+half)*16 + idx
__global__ void wconv_g(const float* __restrict__ W, u16* __restrict__ Wt) {
  __shared__ float tile[32][33];
  const int n0 = blockIdx.x * 32, k0 = blockIdx.y * 32;
  const int tx = threadIdx.x, ty = threadIdx.y;
#pragma unroll
  for (int i = 0; i < 4; ++i)
    tile[ty + 8 * i][tx] = W[(size_t)(k0 + ty + 8 * i) * 8192 + n0 + tx];
  __syncthreads();
#pragma unroll
  for (int i = 0; i < 4; ++i) {
    const int n = n0 + ty + 8 * i;
    const int half = n >> 12, c = n & 4095;
    const int blk = c >> 7, cc = c & 127;
    const int wcol = cc >> 5, rem = cc & 31;
    const int sub = rem >> 4, idx = rem & 15;
    const int p = blk * 256 + wcol * 64 + (sub * 2 + half) * 16 + idx;
    Wt[(size_t)p * 1024 + k0 + tx] = f2bf(tile[tx][ty + 8 * i]);
  }
}

// ---------------- simple f32 -> bf16 convert (encoder states)
__global__ void cvt_bf(const float* __restrict__ in, u16* __restrict__ out, int n) {
  int i = blockIdx.x * 256 + threadIdx.x;
  if (i < n) out[i] = f2bf(in[i]);
}

// ---------------- V transpose pre-pass: V rows (s) -> Vt[(bh*64+d)*S + t0*64 + pos(s)]
__global__ __launch_bounds__(256)
void vtrans(const u16* __restrict__ V, int ldv, int hoff, u16* __restrict__ Vt, int S) {
  __shared__ u16 tile[64][72];
  const int t0 = blockIdx.x, bh = blockIdx.y;
  const int b = bh >> 4, hc = (bh & 15) * 64 + hoff;
  const int tid = threadIdx.x;
  const int r = tid >> 2, dq = (tid & 3) * 16;
  const int pos = ((r >> 5) << 5) | (((r >> 2) & 3) << 3) | (((r >> 4) & 1) << 2) | (r & 3);
  const size_t grow = ((size_t)b * S + t0 * 64 + r) * ldv + hc + dq;
  u16x8 v1 = *(const u16x8*)&V[grow];
  u16x8 v2 = *(const u16x8*)&V[grow + 8];
#pragma unroll
  for (int j = 0; j < 8; ++j) {
    tile[dq + j][pos] = v1[j];
    tile[dq + 8 + j][pos] = v2[j];
  }
  __syncthreads();
  const int d = tid >> 2, c = (tid & 3) * 16;
  u16x8 o1, o2;
#pragma unroll
  for (int j = 0; j < 8; ++j) { o1[j] = tile[d][c + j]; o2[j] = tile[d][c + 8 + j]; }
  *(u16x8*)&Vt[((size_t)bh * 64 + d) * S + t0 * 64 + c] = o1;
  *(u16x8*)&Vt[((size_t)bh * 64 + d) * S + t0 * 64 + c + 8] = o2;
}

// ---------------- LayerNorm: row of 1024 f32 -> bf16
__global__ __launch_bounds__(256)
void ln_fwd(const float* __restrict__ X, const float* __restrict__ wt,
            const float* __restrict__ bs, u16* __restrict__ Y) {
  const int row = blockIdx.x, t = threadIdx.x;
  const float4 v = *(const float4*)&X[(size_t)row * 1024 + t * 4];
  float s = v.x + v.y + v.z + v.w;
  float s2 = v.x * v.x + v.y * v.y + v.z * v.z + v.w * v.w;
#pragma unroll
  for (int off = 32; off > 0; off >>= 1) {
    s += __shfl_xor(s, off);
    s2 += __shfl_xor(s2, off);
  }
  __shared__ float rs[4], rs2[4];
  const int w = t >> 6;
  if ((t & 63) == 0) { rs[w] = s; rs2[w] = s2; }
  __syncthreads();
  s = rs[0] + rs[1] + rs[2] + rs[3];
  s2 = rs2[0] + rs2[1] + rs2[2] + rs2[3];
  const float mu = s * (1.0f / 1024.0f);
  const float var = s2 * (1.0f / 1024.0f) - mu * mu;
  const float rstd = rsqrtf(var + 1e-5f);
  const float4 wv = *(const float4*)&wt[t * 4];
  const float4 bv = *(const float4*)&bs[t * 4];
  u16x4 o;
  o[0] = f2bf((v.x - mu) * rstd * wv.x + bv.x);
  o[1] = f2bf((v.y - mu) * rstd * wv.y + bv.y);
  o[2] = f2bf((v.z - mu) * rstd * wv.z + bv.z);
  o[3] = f2bf((v.w - mu) * rstd * wv.w + bv.w);
  *(u16x4*)&Y[(size_t)row * 1024 + t * 4] = o;
}

// ---------------- 128xTN 2-phase GEMM (N=1024-class shapes), XCD- + T2-swizzled
template<int TN>
__global__ __launch_bounds__(256, 4)
void gemm_bf16(const u16* __restrict__ A, int lda, const u16* __restrict__ Bt,
               int M, int N, int K, const float* __restrict__ bias,
               const float* __restrict__ resid, float oscale,
               float* __restrict__ outF, u16* __restrict__ outB) {
  constexpr int WNV = (TN == 128) ? 2 : 1;
  constexpr int WMV = 4 / WNV;
  constexpr int WM = 128 / WMV;
  constexpr int WN = TN / WNV;
  constexpr int MI = WM / 16, NI = WN / 16;
  __shared__ __align__(16) u16 Al[128 * 64];
  __shared__ __align__(16) u16 Bl[TN * 64];
  const int tid = threadIdx.x;
  const int w = tid >> 6, l = tid & 63, lo = l & 15, g = l >> 4;
  const int gx = gridDim.x, nwg = gx * gridDim.y;
  const int lin = blockIdx.y * gx + blockIdx.x;
  const int q = nwg >> 3, r = nwg & 7;
  const int xcd = lin & 7, pos = lin >> 3;
  const int sid = (xcd < r ? xcd * (q + 1) : r * (q + 1) + (xcd - r) * q) + pos;
  const int bm = (sid % gx) * 128, bn = (sid / gx) * TN;
  const int wm = (w / WNV) * WM, wn = (w % WNV) * WN;
  const int swz = (lo & 7) << 3;
  f32x4 acc[MI][NI] = {};

  for (int k0 = 0; k0 < K; k0 += 64) {
#pragma unroll
    for (int p = 0; p < 4; ++p) {
      int idx = p * 256 + tid;
      int row = idx >> 3, c = idx & 7;
      gld16(A + (size_t)(bm + row) * lda + k0 + ((c ^ (row & 7)) << 3), &Al[idx * 8]);
    }
#pragma unroll
    for (int p = 0; p < TN / 32; ++p) {
      int idx = p * 256 + tid;
      int row = idx >> 3, c = idx & 7;
      gld16(Bt + (size_t)(bn + row) * K + k0 + ((c ^ (row & 7)) << 3), &Bl[idx * 8]);
    }
    asm volatile("s_waitcnt vmcnt(0)" ::: "memory");
    __syncthreads();
#pragma unroll
    for (int ks = 0; ks < 2; ++ks) {
      bf16x8 af[MI], bf[NI];
#pragma unroll
      for (int i = 0; i < MI; ++i)
        af[i] = *(const bf16x8*)&Al[(wm + i * 16 + lo) * 64 + ((ks * 32 + g * 8) ^ swz)];
#pragma unroll
      for (int i = 0; i < NI; ++i)
        bf[i] = *(const bf16x8*)&Bl[(wn + i * 16 + lo) * 64 + ((ks * 32 + g * 8) ^ swz)];
#pragma unroll
      for (int mi = 0; mi < MI; ++mi)
#pragma unroll
        for (int ni = 0; ni < NI; ++ni)
          acc[mi][ni] = __builtin_amdgcn_mfma_f32_16x16x32_bf16(af[mi], bf[ni], acc[mi][ni], 0, 0, 0);
    }
    __syncthreads();
  }

#pragma unroll
  for (int mi = 0; mi < MI; ++mi) {
#pragma unroll
    for (int ni = 0; ni < NI; ++ni) {
      const int col = bn + wn + ni * 16 + lo;
      const float bb = bias ? bias[col] : 0.0f;
      const int row0 = bm + wm + mi * 16 + g * 4;
#pragma unroll
      for (int rr = 0; rr < 4; ++rr) {
        const size_t off = (size_t)(row0 + rr) * N + col;
        float v = acc[mi][ni][rr] * oscale + bb;
        if (resid) v += resid[off];
        if (outF) outF[off] = v;
        else outB[off] = f2bf(v);
      }
    }
  }
}

// ---------------- 256x256 8-phase GEMM; balanced ds_reads, compiler-counted lgkm
// MODE 0: normal epilogue. MODE 1: register-paired GEGLU epilogue:
// acc[mi][2s] = h1, acc[mi][2s+1] = h2 for the SAME output col; out = h1*gelu(h2).
template<int MODE>
__global__ __launch_bounds__(512, 2)
void gemm256(const u16* __restrict__ A, int lda, const u16* __restrict__ Bt,
             int M, int N, int K, const float* __restrict__ bias,
             const float* __restrict__ resid, float oscale,
             float* __restrict__ outF, u16* __restrict__ outB) {
  __shared__ __align__(16) u16 sm[65536];   // [2 dbuf][A 16384 | B 16384] u16
  const int tid = threadIdx.x;
  const int w = tid >> 6, l = tid & 63, lo = l & 15, g = l >> 4;
  const int wrow = w >> 2, wcol = w & 3;
  const int gx = gridDim.x;
  const int nwg = gx * gridDim.y;
  const int lin = blockIdx.y * gx + blockIdx.x;
  const int q = nwg >> 3, r = nwg & 7;
  const int xcd = lin & 7, pos = lin >> 3;
  const int sid = (xcd < r ? xcd * (q + 1) : r * (q + 1) + (xcd - r) * q) + pos;
  const int bm = (sid % gx) * 256, bn = (sid / gx) * 256;

  const int NT = K >> 6;
  const int swz = (lo & 7) << 3;
  f32x4 acc[8][4] = {};

  stage_half(Bt + (size_t)bn * K, K, sm + 16384, tid);
  stage_half(Bt + (size_t)(bn + 128) * K, K, sm + 16384 + 8192, tid);
  stage_half(A + (size_t)bm * lda, lda, sm, tid);
  stage_half(A + (size_t)(bm + 128) * lda, lda, sm + 8192, tid);
  if (NT > 1) {
    stage_half(Bt + (size_t)bn * K + 64, K, sm + 32768 + 16384, tid);
    stage_half(Bt + (size_t)(bn + 128) * K + 64, K, sm + 32768 + 16384 + 8192, tid);
    stage_half(A + (size_t)bm * lda + 64, lda, sm + 32768, tid);
  }
  asm volatile("s_waitcnt vmcnt(6)" ::: "memory");
  __builtin_amdgcn_s_barrier();

  for (int t = 0; t < NT; ++t) {
    u16* Ab_ = sm + (t & 1) * 32768;
    u16* Bb_ = Ab_ + 16384;
    bf16x8 a0[4][2], a1[4][2], bfr[4][2];
    // ---- phase 0: read a0 + all B; stage A.h1(t+1); MFMA (m0,n01)
#pragma unroll
    for (int mf = 0; mf < 4; ++mf) {
      const int rowi = wrow * 128 + mf * 16 + lo;
#pragma unroll
      for (int kk = 0; kk < 2; ++kk)
        a0[mf][kk] = *(const bf16x8*)&Ab_[rowi * 64 + ((kk * 32 + g * 8) ^ swz)];
    }
#pragma unroll
    for (int nf = 0; nf < 4; ++nf) {
      const int rowi = wcol * 64 + nf * 16 + lo;
#pragma unroll
      for (int kk = 0; kk < 2; ++kk)
        bfr[nf][kk] = *(const bf16x8*)&Bb_[rowi * 64 + ((kk * 32 + g * 8) ^ swz)];
    }
    if (t + 1 < NT)
      stage_half(A + (size_t)(bm + 128) * lda + (t + 1) * 64, lda,
                 sm + ((t + 1) & 1) * 32768 + 8192, tid);
    __builtin_amdgcn_s_barrier();
    __builtin_amdgcn_s_setprio(1);
#pragma unroll
    for (int mf = 0; mf < 4; ++mf)
#pragma unroll
      for (int nf = 0; nf < 2; ++nf)
#pragma unroll
        for (int kk = 0; kk < 2; ++kk)
          acc[mf][nf] = __builtin_amdgcn_mfma_f32_16x16x32_bf16(a0[mf][kk], bfr[nf][kk], acc[mf][nf], 0, 0, 0);
    __builtin_amdgcn_s_setprio(0);
    __builtin_amdgcn_s_barrier();
    // ---- phase 1: read a1; stage B.h0(t+2); MFMA (m0,n23)
#pragma unroll
    for (int mf = 0; mf < 4; ++mf) {
      const int rowi = wrow * 128 + 64 + mf * 16 + lo;
#pragma unroll
      for (int kk = 0; kk < 2; ++kk)
        a1[mf][kk] = *(const bf16x8*)&Ab_[rowi * 64 + ((kk * 32 + g * 8) ^ swz)];
    }
    if (t + 2 < NT)
      stage_half(Bt + (size_t)bn * K + (t + 2) * 64, K,
                 sm + (t & 1) * 32768 + 16384, tid);
    __builtin_amdgcn_s_barrier();
    __builtin_amdgcn_s_setprio(1);
#pragma unroll
    for (int mf = 0; mf < 4; ++mf)
#pragma unroll
      for (int nf = 2; nf < 4; ++nf)
#pragma unroll
        for (int kk = 0; kk < 2; ++kk)
          acc[mf][nf] = __builtin_amdgcn_mfma_f32_16x16x32_bf16(a0[mf][kk], bfr[nf][kk], acc[mf][nf], 0, 0, 0);
    __builtin_amdgcn_s_setprio(0);
    __builtin_amdgcn_s_barrier();
    // ---- phase 2: stage B.h1(t+2); MFMA (m1,n01)
    if (t + 2 < NT)
      stage_half(Bt + (size_t)(bn + 128) * K + (t + 2) * 64, K,
                 sm + (t & 1) * 32768 + 16384 + 8192, tid);
    __builtin_amdgcn_s_barrier();
    __builtin_amdgcn_s_setprio(1);
#pragma unroll
    for (int mf = 0; mf < 4; ++mf)
#pragma unroll
      for (int nf = 0; nf < 2; ++nf)
#pragma unroll
        for (int kk = 0; kk < 2; ++kk)
          acc[4 + mf][nf] = __builtin_amdgcn_mfma_f32_16x16x32_bf16(a1[mf][kk], bfr[nf][kk], acc[4 + mf][nf], 0, 0, 0);
    __builtin_amdgcn_s_setprio(0);
    __builtin_amdgcn_s_barrier();
    // ---- phase 3: stage A.h0(t+2); MFMA (m1,n23); counted vmcnt (0 at tail)
    if (t + 2 < NT)
      stage_half(A + (size_t)bm * lda + (t + 2) * 64, lda,
                 sm + (t & 1) * 32768, tid);
    __builtin_amdgcn_s_barrier();
    __builtin_amdgcn_s_setprio(1);
#pragma unroll
    for (int mf = 0; mf < 4; ++mf)
#pragma unroll
      for (int nf = 2; nf < 4; ++nf)
#pragma unroll
        for (int kk = 0; kk < 2; ++kk)
          acc[4 + mf][nf] = __builtin_amdgcn_mfma_f32_16x16x32_bf16(a1[mf][kk], bfr[nf][kk], acc[4 + mf][nf], 0, 0, 0);
    __builtin_amdgcn_s_setprio(0);
    if (t + 2 < NT) asm volatile("s_waitcnt vmcnt(6)" ::: "memory");
    else            asm volatile("s_waitcnt vmcnt(0)" ::: "memory");
    __builtin_amdgcn_s_barrier();
  }

  if (MODE == 1) {
    // register-paired GEGLU: acc[mi][2s]=h1, acc[mi][2s+1]=h2, same out col.
    const int obase = bn >> 1;
#pragma unroll
    for (int mi = 0; mi < 8; ++mi) {
#pragma unroll
      for (int sub = 0; sub < 2; ++sub) {
        const int col = obase + wcol * 32 + sub * 16 + lo;
        const float b1 = bias[col];
        const float b2 = bias[4096 + col];
#pragma unroll
        for (int rr = 0; rr < 4; ++rr) {
          const int rowi = wrow * 128 + mi * 16 + g * 4 + rr;
          const float h1 = acc[mi][sub * 2][rr] + b1;
          const float h2 = acc[mi][sub * 2 + 1][rr] + b2;
          const float ge = 0.5f * h2 * (1.0f + erff(h2 * 0.70710678118f));
          outB[(size_t)(bm + rowi) * 4096 + col] = f2bf(h1 * ge);
        }
      }
    }
    return;
  }

#pragma unroll
  for (int mi = 0; mi < 8; ++mi) {
#pragma unroll
    for (int ni = 0; ni < 4; ++ni) {
      const int col = bn + wcol * 64 + ni * 16 + lo;
      const float bb = bias ? bias[col] : 0.0f;
      const int row0 = bm + wrow * 128 + mi * 16 + g * 4;
#pragma unroll
      for (int rr = 0; rr < 4; ++rr) {
        const size_t off = (size_t)(row0 + rr) * N + col;
        float v = acc[mi][ni][rr] * oscale + bb;
        if (resid) v += resid[off];
        if (outF) outF[off] = v;
        else outB[off] = f2bf(v);
      }
    }
  }
}

// ---------------- fused flash attention v5: QK-ahead pipeline + VALU-diet softmax.
// lsum via MFMA row-sum (P x ones, accumulates straight into lrow, layout = C-layout
// q = g*4+rr so the epilogue needs no shuffles); defer-max rescale (THR=8, base-2).
__global__ __launch_bounds__(256, 4)
void attn_fwd(const u16* __restrict__ Q, int ldq, const u16* __restrict__ K, int ldk,
              const u16* __restrict__ Vt, u16* __restrict__ O, int T, int S) {
  __shared__ __align__(16) u16 Kl[2][4096];
  __shared__ __align__(16) u16 Vl[2][4096];
  const int tid = threadIdx.x, w = tid >> 6, l = tid & 63, lo = l & 15, g = l >> 4;
  const int nwg = gridDim.x * gridDim.y;
  const int n = blockIdx.y * gridDim.x + blockIdx.x;
  const int sid = (n & 7) * (nwg >> 3) + (n >> 3);
  const int qt = sid % gridDim.x, bh = sid / gridDim.x;
  const int b = bh >> 4, h = bh & 15, hc = h * 64;
  const int q0 = qt * 64 + w * 16;
  const size_t qrow = (size_t)b * T + q0;
  const size_t krow0 = (size_t)b * S;
  const size_t vrow0 = (size_t)bh * 64;

  bf16x8 qf[2];
#pragma unroll
  for (int kk = 0; kk < 2; ++kk)
    qf[kk] = *(const bf16x8*)&Q[(qrow + lo) * ldq + hc + kk * 32 + g * 8];

  // all-ones bf16 fragment for MFMA row-sum
  union { u16 u[8]; bf16x8 v; } onesc;
#pragma unroll
  for (int j = 0; j < 8; ++j) onesc.u[j] = 0x3F80;

  f32x4 oa[4] = {};
  f32x4 lrow = {};
  float m = -1e30f;

  const int srow = tid >> 3;
  const int scol = (((tid & 7) ^ (srow & 7)) << 3);
  const int ntile = S >> 6;

  // prologue: K(0)->Kl[0], K(1)->Kl[1], V(0)->Vl[0]; then QK(0)->sC
#pragma unroll
  for (int c = 0; c < 2; ++c)
    gld16(K + (krow0 + c * 32 + srow) * ldk + hc + scol, &Kl[0][c * 2048 + tid * 8]);
#pragma unroll
  for (int c = 0; c < 2; ++c)
    gld16(K + (krow0 + 64 + c * 32 + srow) * ldk + hc + scol, &Kl[1][c * 2048 + tid * 8]);
#pragma unroll
  for (int c = 0; c < 2; ++c)
    gld16(Vt + (vrow0 + c * 32 + srow) * S + scol, &Vl[0][c * 2048 + tid * 8]);
  asm volatile("s_waitcnt vmcnt(0)" ::: "memory");
  __builtin_amdgcn_s_barrier();

  f32x4 sC[4] = {};
#pragma unroll
  for (int c = 0; c < 4; ++c)
#pragma unroll
    for (int kk = 0; kk < 2; ++kk) {
      bf16x8 kf = *(const bf16x8*)&Kl[0][(c * 16 + lo) * 64 +
                                        ((kk * 32 + g * 8) ^ ((lo & 7) << 3))];
      sC[c] = __builtin_amdgcn_mfma_f32_16x16x32_bf16(kf, qf[kk], sC[c], 0, 0, 0);
    }
  asm volatile("s_waitcnt lgkmcnt(0)" ::: "memory");
  __builtin_amdgcn_s_barrier();

  for (int t0 = 0; t0 < ntile; ++t0) {
    const int cur = t0 & 1, nxt = cur ^ 1;
    // stage K(t+2) -> Kl[cur], V(t+1) -> Vl[nxt]
    if (t0 + 2 < ntile) {
#pragma unroll
      for (int c = 0; c < 2; ++c)
        gld16(K + (krow0 + (t0 + 2) * 64 + c * 32 + srow) * ldk + hc + scol,
              &Kl[cur][c * 2048 + tid * 8]);
    }
    if (t0 + 1 < ntile) {
#pragma unroll
      for (int c = 0; c < 2; ++c)
        gld16(Vt + (vrow0 + c * 32 + srow) * S + (t0 + 1) * 64 + scol,
              &Vl[nxt][c * 2048 + tid * 8]);
    }
    if (t0 + 2 < ntile)      asm volatile("s_waitcnt vmcnt(4)" ::: "memory");
    else if (t0 + 1 < ntile) asm volatile("s_waitcnt vmcnt(2)" ::: "memory");
    else                     asm volatile("s_waitcnt vmcnt(0)" ::: "memory");
    __builtin_amdgcn_s_barrier();

    // QK(t+1) issue first (fills MFMA pipe under softmax VALU)
    f32x4 sN[4] = {};
    if (t0 + 1 < ntile) {
#pragma unroll
      for (int c = 0; c < 4; ++c)
#pragma unroll
        for (int kk = 0; kk < 2; ++kk) {
          bf16x8 kf = *(const bf16x8*)&Kl[nxt][(c * 16 + lo) * 64 +
                                              ((kk * 32 + g * 8) ^ ((lo & 7) << 3))];
          sN[c] = __builtin_amdgcn_mfma_f32_16x16x32_bf16(kf, qf[kk], sN[c], 0, 0, 0);
        }
    }

    // online softmax on sC (tile t0), base-2, defer-max THR=8
    float mx = fmaxf(fmaxf(fmaxf(sC[0][0], sC[0][1]), fmaxf(sC[0][2], sC[0][3])),
                     fmaxf(fmaxf(sC[1][0], sC[1][1]), fmaxf(sC[1][2], sC[1][3])));
    mx = fmaxf(mx, fmaxf(fmaxf(fmaxf(sC[2][0], sC[2][1]), fmaxf(sC[2][2], sC[2][3])),
                         fmaxf(fmaxf(sC[3][0], sC[3][1]), fmaxf(sC[3][2], sC[3][3]))));
    mx = fmaxf(mx, __shfl_xor(mx, 16));
    mx = fmaxf(mx, __shfl_xor(mx, 32));
    if (!__all(mx <= m + 8.0f)) {
      const float mn = fmaxf(m, mx);
      const float al = exp2f(m - mn);
      m = mn;
      f32x4 arv;
#pragma unroll
      for (int rr = 0; rr < 4; ++rr) arv[rr] = __shfl(al, 20 * g + rr);
#pragma unroll
      for (int dn = 0; dn < 4; ++dn) oa[dn] *= arv;
      lrow *= arv;
    }
#pragma unroll
    for (int c = 0; c < 4; ++c)
#pragma unroll
      for (int rr = 0; rr < 4; ++rr)
        sC[c][rr] = exp2f(sC[c][rr] - m);

    union { uint32_t u[4]; bf16x8 v; } af[2];
#pragma unroll
    for (int ks = 0; ks < 2; ++ks) {
      af[ks].u[0] = cvtpk(sC[2 * ks][0], sC[2 * ks][1]);
      af[ks].u[1] = cvtpk(sC[2 * ks][2], sC[2 * ks][3]);
      af[ks].u[2] = cvtpk(sC[2 * ks + 1][0], sC[2 * ks + 1][1]);
      af[ks].u[3] = cvtpk(sC[2 * ks + 1][2], sC[2 * ks + 1][3]);
    }
    // row-sum via MFMA: lrow += P x ones (C-layout: lrow[rr] <-> q = g*4+rr)
    lrow = __builtin_amdgcn_mfma_f32_16x16x32_bf16(af[0].v, onesc.v, lrow, 0, 0, 0);
    lrow = __builtin_amdgcn_mfma_f32_16x16x32_bf16(af[1].v, onesc.v, lrow, 0, 0, 0);
    // PV(t0) from Vl[cur]
#pragma unroll
    for (int dn = 0; dn < 4; ++dn)
#pragma unroll
      for (int ks = 0; ks < 2; ++ks) {
        bf16x8 vf = *(const bf16x8*)&Vl[cur][(dn * 16 + lo) * 64 +
                                            ((ks * 32 + g * 8) ^ ((lo & 7) << 3))];
        oa[dn] = __builtin_amdgcn_mfma_f32_16x16x32_bf16(af[ks].v, vf, oa[dn], 0, 0, 0);
      }
    asm volatile("s_waitcnt lgkmcnt(0)" ::: "memory");
    __builtin_amdgcn_s_barrier();
#pragma unroll
    for (int c = 0; c < 4; ++c) sC[c] = sN[c];
  }

#pragma unroll
  for (int dn = 0; dn < 4; ++dn)
#pragma unroll
    for (int rr = 0; rr < 4; ++rr)
      O[(qrow + g * 4 + rr) * 1024 + hc + dn * 16 + lo] = f2bf(oa[dn][rr] / lrow[rr]);
}

extern "C" void kernel_launch(void* const* d_in, const int* in_sizes, int n_in,
                              void* d_out, int out_size, void* d_ws, size_t ws_size,
                              hipStream_t stream) {
  const float* x      = (const float*)d_in[0];
  const float* enc    = (const float*)d_in[1];
  const float* ln1_w  = (const float*)d_in[2];
  const float* ln1_b  = (const float*)d_in[3];
  const float* a1_wq  = (const float*)d_in[4];
  const float* a1_wk  = (const float*)d_in[5];
  const float* a1_wv  = (const float*)d_in[6];
  const float* a1_wo  = (const float*)d_in[7];
  const float* a1_bo  = (const float*)d_in[8];
  const float* ln2_w  = (const float*)d_in[9];
  const float* ln2_b  = (const float*)d_in[10];
  const float* a2_wq  = (const float*)d_in[11];
  const float* a2_wk  = (const float*)d_in[12];
  const float* a2_wv  = (const float*)d_in[13];
  const float* a2_wo  = (const float*)d_in[14];
  const float* a2_bo  = (const float*)d_in[15];
  const float* ln3_w  = (const float*)d_in[16];
  const float* ln3_b  = (const float*)d_in[17];
  const float* ff_w1  = (const float*)d_in[18];
  const float* ff_b1  = (const float*)d_in[19];
  const float* ff_w2  = (const float*)d_in[20];
  const float* ff_b2  = (const float*)d_in[21];

  char* ws = (char*)d_ws;
  const size_t MB = 1u << 20;
  u16* wqkv1t = (u16*)(ws + 0 * MB);              // 3072x1024 = 6 MB
  u16* wo1t   = (u16*)(ws + 6 * MB);
  u16* wq2t   = (u16*)(ws + 8 * MB);
  u16* wo2t   = (u16*)(ws + 10 * MB);
  u16* wkv2t  = (u16*)(ws + 12 * MB);             // 2048x64 = 256 KB
  u16* encb   = (u16*)(ws + 12 * MB + 512 * 1024);
  u16* w1t    = (u16*)(ws + 13 * MB);             // 16 MB (geglu-paired)
  u16* w2t    = (u16*)(ws + 29 * MB);             // 8 MB
  float* x2   = (float*)(ws + 37 * MB);           // 16 MB (live from wo2 on)
  u16* Vt1    = (u16*)(ws + 37 * MB);             // 8 MB (dead before wo2)
  u16* Vt2    = (u16*)(ws + 45 * MB);             // 2 MB (dead before wo2)
  u16* KVb    = (u16*)(ws + 47 * MB);             // 1024x2048 = 4 MB
  u16* hbuf   = (u16*)(ws + 53 * MB);             // 8 MB
  u16* qkv    = (u16*)(ws + 61 * MB);             // 24 MB
  u16* Qb     = (u16*)(ws + 61 * MB);             // cross-attn reuse
  u16* Ab     = (u16*)(ws + 85 * MB);             // 8 MB
  float* x1   = (float*)(ws + 93 * MB);           // 16 MB -> 109
  u16* gq     = (u16*)(ws + 61 * MB);             // 4096x4096 = 32 MB (reuses qkv/Ab)

  const float SCL = 0.125f * 1.44269504f;
  const dim3 tb(32, 8);
  {
    WB wb;
    wb.src[0] = a1_wq; wb.dst[0] = wqkv1t;               wb.scale[0] = SCL;
    wb.src[1] = a1_wk; wb.dst[1] = wqkv1t + 1024 * 1024; wb.scale[1] = 1.0f;
    wb.src[2] = a1_wv; wb.dst[2] = wqkv1t + 2048 * 1024; wb.scale[2] = 1.0f;
    wb.src[3] = a1_wo; wb.dst[3] = wo1t;                 wb.scale[3] = 1.0f;
    wb.src[4] = a2_wq; wb.dst[4] = wq2t;                 wb.scale[4] = SCL;
    wb.src[5] = a2_wo; wb.dst[5] = wo2t;                 wb.scale[5] = 1.0f;
    wconv_b<<<dim3(32, 32, 6), tb, 0, stream>>>(wb, 1024, 1024);
    WB wb2;
    wb2.src[0] = a2_wk; wb2.dst[0] = wkv2t;             wb2.scale[0] = 1.0f;
    wb2.src[1] = a2_wv; wb2.dst[1] = wkv2t + 64 * 1024; wb2.scale[1] = 1.0f;
    wb2.src[2] = a2_wk; wb2.dst[2] = wkv2t;             wb2.scale[2] = 1.0f;
    wb2.src[3] = a2_wk; wb2.dst[3] = wkv2t;             wb2.scale[3] = 1.0f;
    wb2.src[4] = a2_wk; wb2.dst[4] = wkv2t;             wb2.scale[4] = 1.0f;
    wb2.src[5] = a2_wk; wb2.dst[5] = wkv2t;             wb2.scale[5] = 1.0f;
    wconv_b<<<dim3(32, 2, 2), tb, 0, stream>>>(wb2, 64, 1024);
  }
  wconv_g<<<dim3(256, 32), tb, 0, stream>>>(ff_w1, w1t);
  wconv_t<<<dim3(32, 128), tb, 0, stream>>>(ff_w2, w2t, 4096, 1024);
  cvt_bf<<<256, 256, 0, stream>>>(enc, encb, 2 * 512 * 64);

  // ---- self-attention sub-block
  ln_fwd<<<4096, 256, 0, stream>>>(x, ln1_w, ln1_b, hbuf);
  gemm256<0><<<dim3(16, 12), 512, 0, stream>>>(hbuf, 1024, wqkv1t, 4096, 3072, 1024, nullptr, nullptr, 1.0f, nullptr, qkv);
  vtrans<<<dim3(32, 32), 256, 0, stream>>>(qkv, 3072, 2048, Vt1, 2048);
  attn_fwd<<<dim3(32, 32), 256, 0, stream>>>(qkv, 3072, qkv + 1024, 3072, Vt1, Ab, 2048, 2048);
  gemm_bf16<64><<<dim3(32, 16), 256, 0, stream>>>(Ab, 1024, wo1t, 4096, 1024, 1024, a1_bo, x, 1.0f, x1, nullptr);

  // ---- cross-attention sub-block
  ln_fwd<<<4096, 256, 0, stream>>>(x1, ln2_w, ln2_b, hbuf);
  gemm_bf16<64><<<dim3(32, 16), 256, 0, stream>>>(hbuf, 1024, wq2t, 4096, 1024, 1024, nullptr, nullptr, 1.0f, nullptr, Qb);
  gemm_bf16<64><<<dim3(8, 32), 256, 0, stream>>>(encb, 64, wkv2t, 1024, 2048, 64, nullptr, nullptr, 1.0f, nullptr, KVb);
  vtrans<<<dim3(8, 32), 256, 0, stream>>>(KVb + 1024, 2048, 0, Vt2, 512);
  attn_fwd<<<dim3(32, 32), 256, 0, stream>>>(Qb, 1024, KVb, 2048, Vt2, Ab, 2048, 512);
  gemm_bf16<64><<<dim3(32, 16), 256, 0, stream>>>(Ab, 1024, wo2t, 4096, 1024, 1024, a2_bo, x1, 1.0f, x2, nullptr);

  // ---- GEGLU feed-forward sub-block (geglu fused into FF1 epilogue)
  ln_fwd<<<4096, 256, 0, stream>>>(x2, ln3_w, ln3_b, hbuf);
  gemm256<1><<<dim3(16, 32), 512, 0, stream>>>(hbuf, 1024, w1t, 4096, 8192, 1024, ff_b1, nullptr, 1.0f, nullptr, gq);
  gemm_bf16<64><<<dim3(32, 16), 256, 0, stream>>>(gq, 4096, w2t, 4096, 1024, 4096, ff_b2, x2, 1.0f, (float*)d_out, nullptr);
}

// Round 11
// 409.740 us; speedup vs baseline: 1.0491x; 1.0201x over previous
//
#include <hip/hip_runtime.h>
#include <hip/hip_bf16.h>
#include <stdint.h>

typedef unsigned short u16;
typedef __bf16 bf16x8 __attribute__((ext_vector_type(8)));
typedef float f32x4 __attribute__((ext_vector_type(4)));
typedef u16 u16x8 __attribute__((ext_vector_type(8)));
typedef u16 u16x4 __attribute__((ext_vector_type(4)));

__device__ __forceinline__ u16 f2bf(float f) {
  union { float f; uint32_t u; } v; v.f = f;
  uint32_t r = v.u + 0x7fffu + ((v.u >> 16) & 1u);
  return (u16)(r >> 16);
}
__device__ __forceinline__ float bf2f(u16 u) {
  union { uint32_t u; float f; } v; v.u = ((uint32_t)u) << 16;
  return v.f;
}
__device__ __forceinline__ uint32_t cvtpk(float a, float b) {
  uint32_t r;
  asm("v_cvt_pk_bf16_f32 %0, %1, %2" : "=v"(r) : "v"(a), "v"(b));
  return r;
}

// async global->LDS, 16B per lane. LDS dest must be linear (base + lane*16).
__device__ __forceinline__ void gld16(const u16* g, u16* l) {
  __builtin_amdgcn_global_load_lds(
      (const __attribute__((address_space(1))) uint32_t*)g,
      (__attribute__((address_space(3))) uint32_t*)l, 16, 0, 0);
}

// ---------------- batched weight convert+transpose: W (K x N, f32) -> Wt (N x K, bf16)
struct WB {
  const float* src[6];
  u16* dst[6];
  float scale[6];
};
__global__ void wconv_b(WB wb, int K, int N) {
  const int z = blockIdx.z;
  const float* __restrict__ W = wb.src[z];
  u16* __restrict__ Wt = wb.dst[z];
  const float scale = wb.scale[z];
  __shared__ float tile[32][33];
  const int n0 = blockIdx.x * 32, k0 = blockIdx.y * 32;
  const int tx = threadIdx.x, ty = threadIdx.y;   // (32, 8)
#pragma unroll
  for (int i = 0; i < 4; ++i)
    tile[ty + 8 * i][tx] = W[(size_t)(k0 + ty + 8 * i) * N + n0 + tx];
  __syncthreads();
#pragma unroll
  for (int i = 0; i < 4; ++i)
    Wt[(size_t)(n0 + ty + 8 * i) * K + k0 + tx] = f2bf(scale * tile[tx][ty + 8 * i]);
}

// plain single-matrix variant (ff_w2)
__global__ void wconv_t(const float* __restrict__ W, u16* __restrict__ Wt, int K, int N) {
  __shared__ float tile[32][33];
  const int n0 = blockIdx.x * 32, k0 = blockIdx.y * 32;
  const int tx = threadIdx.x, ty = threadIdx.y;
#pragma unroll
  for (int i = 0; i < 4; ++i)
    tile[ty + 8 * i][tx] = W[(size_t)(k0 + ty + 8 * i) * N + n0 + tx];
  __syncthreads();
#pragma unroll
  for (int i = 0; i < 4; ++i)
    Wt[(size_t)(n0 + ty + 8 * i) * K + k0 + tx] = f2bf(tile[tx][ty + 8 * i]);
}

// ff_w1 convert with fragment-paired GEGLU rows:
// orig col n = half*4096 + blk*128 + wcol*32 + sub*16 + idx
// -> dst row p = blk*256 + wcol*64 + (sub*2+half)*16 + idx
__global__ void wconv_g(const float* __restrict__ W, u16* __restrict__ Wt) {
  __shared__ float tile[32][33];
  const int n0 = blockIdx.x * 32, k0 = blockIdx.y * 32;
  const int tx = threadIdx.x, ty = threadIdx.y;
#pragma unroll
  for (int i = 0; i < 4; ++i)
    tile[ty + 8 * i][tx] = W[(size_t)(k0 + ty + 8 * i) * 8192 + n0 + tx];
  __syncthreads();
#pragma unroll
  for (int i = 0; i < 4; ++i) {
    const int n = n0 + ty + 8 * i;
    const int half = n >> 12, c = n & 4095;
    const int blk = c >> 7, cc = c & 127;
    const int wcol = cc >> 5, rem = cc & 31;
    const int sub = rem >> 4, idx = rem & 15;
    const int p = blk * 256 + wcol * 64 + (sub * 2 + half) * 16 + idx;
    Wt[(size_t)p * 1024 + k0 + tx] = f2bf(tile[tx][ty + 8 * i]);
  }
}

// ---------------- simple f32 -> bf16 convert (encoder states)
__global__ void cvt_bf(const float* __restrict__ in, u16* __restrict__ out, int n) {
  int i = blockIdx.x * 256 + threadIdx.x;
  if (i < n) out[i] = f2bf(in[i]);
}

// ---------------- V transpose pre-pass: V rows (s) -> Vt[(bh*64+d)*S + t0*64 + pos(s)]
__global__ __launch_bounds__(256)
void vtrans(const u16* __restrict__ V, int ldv, int hoff, u16* __restrict__ Vt, int S) {
  __shared__ u16 tile[64][72];
  const int t0 = blockIdx.x, bh = blockIdx.y;
  const int b = bh >> 4, hc = (bh & 15) * 64 + hoff;
  const int tid = threadIdx.x;
  const int r = tid >> 2, dq = (tid & 3) * 16;
  const int pos = ((r >> 5) << 5) | (((r >> 2) & 3) << 3) | (((r >> 4) & 1) << 2) | (r & 3);
  const size_t grow = ((size_t)b * S + t0 * 64 + r) * ldv + hc + dq;
  u16x8 v1 = *(const u16x8*)&V[grow];
  u16x8 v2 = *(const u16x8*)&V[grow + 8];
#pragma unroll
  for (int j = 0; j < 8; ++j) {
    tile[dq + j][pos] = v1[j];
    tile[dq + 8 + j][pos] = v2[j];
  }
  __syncthreads();
  const int d = tid >> 2, c = (tid & 3) * 16;
  u16x8 o1, o2;
#pragma unroll
  for (int j = 0; j < 8; ++j) { o1[j] = tile[d][c + j]; o2[j] = tile[d][c + 8 + j]; }
  *(u16x8*)&Vt[((size_t)bh * 64 + d) * S + t0 * 64 + c] = o1;
  *(u16x8*)&Vt[((size_t)bh * 64 + d) * S + t0 * 64 + c + 8] = o2;
}

// ---------------- LayerNorm: row of 1024 f32 -> bf16
__global__ __launch_bounds__(256)
void ln_fwd(const float* __restrict__ X, const float* __restrict__ wt,
            const float* __restrict__ bs, u16* __restrict__ Y) {
  const int row = blockIdx.x, t = threadIdx.x;
  const float4 v = *(const float4*)&X[(size_t)row * 1024 + t * 4];
  float s = v.x + v.y + v.z + v.w;
  float s2 = v.x * v.x + v.y * v.y + v.z * v.z + v.w * v.w;
#pragma unroll
  for (int off = 32; off > 0; off >>= 1) {
    s += __shfl_xor(s, off);
    s2 += __shfl_xor(s2, off);
  }
  __shared__ float rs[4], rs2[4];
  const int w = t >> 6;
  if ((t & 63) == 0) { rs[w] = s; rs2[w] = s2; }
  __syncthreads();
  s = rs[0] + rs[1] + rs[2] + rs[3];
  s2 = rs2[0] + rs2[1] + rs2[2] + rs2[3];
  const float mu = s * (1.0f / 1024.0f);
  const float var = s2 * (1.0f / 1024.0f) - mu * mu;
  const float rstd = rsqrtf(var + 1e-5f);
  const float4 wv = *(const float4*)&wt[t * 4];
  const float4 bv = *(const float4*)&bs[t * 4];
  u16x4 o;
  o[0] = f2bf((v.x - mu) * rstd * wv.x + bv.x);
  o[1] = f2bf((v.y - mu) * rstd * wv.y + bv.y);
  o[2] = f2bf((v.z - mu) * rstd * wv.z + bv.z);
  o[3] = f2bf((v.w - mu) * rstd * wv.w + bv.w);
  *(u16x4*)&Y[(size_t)row * 1024 + t * 4] = o;
}

// ---------------- 128xTN 2-phase GEMM (N=1024-class shapes), XCD- + T2-swizzled
template<int TN>
__global__ __launch_bounds__(256, 4)
void gemm_bf16(const u16* __restrict__ A, int lda, const u16* __restrict__ Bt,
               int M, int N, int K, const float* __restrict__ bias,
               const float* __restrict__ resid, float oscale,
               float* __restrict__ outF, u16* __restrict__ outB) {
  constexpr int WNV = (TN == 128) ? 2 : 1;
  constexpr int WMV = 4 / WNV;
  constexpr int WM = 128 / WMV;
  constexpr int WN = TN / WNV;
  constexpr int MI = WM / 16, NI = WN / 16;
  __shared__ __align__(16) u16 Al[128 * 64];
  __shared__ __align__(16) u16 Bl[TN * 64];
  const int tid = threadIdx.x;
  const int w = tid >> 6, l = tid & 63, lo = l & 15, g = l >> 4;
  const int gx = gridDim.x, nwg = gx * gridDim.y;
  const int lin = blockIdx.y * gx + blockIdx.x;
  const int q = nwg >> 3, r = nwg & 7;
  const int xcd = lin & 7, pos = lin >> 3;
  const int sid = (xcd < r ? xcd * (q + 1) : r * (q + 1) + (xcd - r) * q) + pos;
  const int bm = (sid % gx) * 128, bn = (sid / gx) * TN;
  const int wm = (w / WNV) * WM, wn = (w % WNV) * WN;
  const int swz = (lo & 7) << 3;
  f32x4 acc[MI][NI] = {};

  for (int k0 = 0; k0 < K; k0 += 64) {
#pragma unroll
    for (int p = 0; p < 4; ++p) {
      int idx = p * 256 + tid;
      int row = idx >> 3, c = idx & 7;
      gld16(A + (size_t)(bm + row) * lda + k0 + ((c ^ (row & 7)) << 3), &Al[idx * 8]);
    }
#pragma unroll
    for (int p = 0; p < TN / 32; ++p) {
      int idx = p * 256 + tid;
      int row = idx >> 3, c = idx & 7;
      gld16(Bt + (size_t)(bn + row) * K + k0 + ((c ^ (row & 7)) << 3), &Bl[idx * 8]);
    }
    asm volatile("s_waitcnt vmcnt(0)" ::: "memory");
    __syncthreads();
#pragma unroll
    for (int ks = 0; ks < 2; ++ks) {
      bf16x8 af[MI], bf[NI];
#pragma unroll
      for (int i = 0; i < MI; ++i)
        af[i] = *(const bf16x8*)&Al[(wm + i * 16 + lo) * 64 + ((ks * 32 + g * 8) ^ swz)];
#pragma unroll
      for (int i = 0; i < NI; ++i)
        bf[i] = *(const bf16x8*)&Bl[(wn + i * 16 + lo) * 64 + ((ks * 32 + g * 8) ^ swz)];
#pragma unroll
      for (int mi = 0; mi < MI; ++mi)
#pragma unroll
        for (int ni = 0; ni < NI; ++ni)
          acc[mi][ni] = __builtin_amdgcn_mfma_f32_16x16x32_bf16(af[mi], bf[ni], acc[mi][ni], 0, 0, 0);
    }
    __syncthreads();
  }

#pragma unroll
  for (int mi = 0; mi < MI; ++mi) {
#pragma unroll
    for (int ni = 0; ni < NI; ++ni) {
      const int col = bn + wn + ni * 16 + lo;
      const float bb = bias ? bias[col] : 0.0f;
      const int row0 = bm + wm + mi * 16 + g * 4;
#pragma unroll
      for (int rr = 0; rr < 4; ++rr) {
        const size_t off = (size_t)(row0 + rr) * N + col;
        float v = acc[mi][ni][rr] * oscale + bb;
        if (resid) v += resid[off];
        if (outF) outF[off] = v;
        else outB[off] = f2bf(v);
      }
    }
  }
}

// stage one 128x64 half-tile from two running per-thread pointers (advance +64/tile)
#define ST2(p0, p1, dst) { gld16(p0, (dst) + tid * 8); gld16(p1, (dst) + 4096 + tid * 8); (p0) += 64; (p1) += 64; }

// ---------------- 256x256 8-phase GEMM; running staging pointers, counted vmcnt
// MODE 0: normal epilogue. MODE 1: register-paired GEGLU epilogue:
// acc[mi][2s] = h1, acc[mi][2s+1] = h2 for the SAME output col; out = h1*gelu(h2).
template<int MODE>
__global__ __launch_bounds__(512, 2)
void gemm256(const u16* __restrict__ A, int lda, const u16* __restrict__ Bt,
             int M, int N, int K, const float* __restrict__ bias,
             const float* __restrict__ resid, float oscale,
             float* __restrict__ outF, u16* __restrict__ outB) {
  __shared__ __align__(16) u16 sm[65536];   // [2 dbuf][A 16384 | B 16384] u16
  const int tid = threadIdx.x;
  const int w = tid >> 6, l = tid & 63, lo = l & 15, g = l >> 4;
  const int wrow = w >> 2, wcol = w & 3;
  const int gx = gridDim.x;
  const int nwg = gx * gridDim.y;
  const int lin = blockIdx.y * gx + blockIdx.x;
  const int q = nwg >> 3, r = nwg & 7;
  const int xcd = lin & 7, pos = lin >> 3;
  const int sid = (xcd < r ? xcd * (q + 1) : r * (q + 1) + (xcd - r) * q) + pos;
  const int bm = (sid % gx) * 256, bn = (sid / gx) * 256;

  const int NT = K >> 6;
  const int swz = (lo & 7) << 3;
  f32x4 acc[8][4] = {};

  // per-thread running staging pointers (strength-reduced addresses)
  const int sr8 = tid >> 3;
  const int sc8 = ((tid & 7) ^ (sr8 & 7)) << 3;
  const u16 *pA0 = A + (size_t)(bm + sr8) * lda + sc8;
  const u16 *pA1 = A + (size_t)(bm + 64 + sr8) * lda + sc8;
  const u16 *pA2 = A + (size_t)(bm + 128 + sr8) * lda + sc8;
  const u16 *pA3 = A + (size_t)(bm + 192 + sr8) * lda + sc8;
  const u16 *pB0 = Bt + (size_t)(bn + sr8) * K + sc8;
  const u16 *pB1 = Bt + (size_t)(bn + 64 + sr8) * K + sc8;
  const u16 *pB2 = Bt + (size_t)(bn + 128 + sr8) * K + sc8;
  const u16 *pB3 = Bt + (size_t)(bn + 192 + sr8) * K + sc8;

  // prologue (same stage order as before)
  ST2(pB0, pB1, sm + 16384);
  ST2(pB2, pB3, sm + 16384 + 8192);
  ST2(pA0, pA1, sm);
  ST2(pA2, pA3, sm + 8192);
  if (NT > 1) {
    ST2(pB0, pB1, sm + 32768 + 16384);
    ST2(pB2, pB3, sm + 32768 + 16384 + 8192);
    ST2(pA0, pA1, sm + 32768);
  }
  asm volatile("s_waitcnt vmcnt(6)" ::: "memory");
  __builtin_amdgcn_s_barrier();

  for (int t = 0; t < NT; ++t) {
    u16* Ab_ = sm + (t & 1) * 32768;
    u16* Bb_ = Ab_ + 16384;
    bf16x8 a0[4][2], a1[4][2], bfr[4][2];
    // ---- phase 0: read a0 + all B; stage A.h1(t+1); MFMA (m0,n01)
#pragma unroll
    for (int mf = 0; mf < 4; ++mf) {
      const int rowi = wrow * 128 + mf * 16 + lo;
#pragma unroll
      for (int kk = 0; kk < 2; ++kk)
        a0[mf][kk] = *(const bf16x8*)&Ab_[rowi * 64 + ((kk * 32 + g * 8) ^ swz)];
    }
#pragma unroll
    for (int nf = 0; nf < 4; ++nf) {
      const int rowi = wcol * 64 + nf * 16 + lo;
#pragma unroll
      for (int kk = 0; kk < 2; ++kk)
        bfr[nf][kk] = *(const bf16x8*)&Bb_[rowi * 64 + ((kk * 32 + g * 8) ^ swz)];
    }
    if (t + 1 < NT)
      ST2(pA2, pA3, sm + ((t + 1) & 1) * 32768 + 8192);
    __builtin_amdgcn_s_barrier();
    __builtin_amdgcn_s_setprio(1);
#pragma unroll
    for (int mf = 0; mf < 4; ++mf)
#pragma unroll
      for (int nf = 0; nf < 2; ++nf)
#pragma unroll
        for (int kk = 0; kk < 2; ++kk)
          acc[mf][nf] = __builtin_amdgcn_mfma_f32_16x16x32_bf16(a0[mf][kk], bfr[nf][kk], acc[mf][nf], 0, 0, 0);
    __builtin_amdgcn_s_setprio(0);
    __builtin_amdgcn_s_barrier();
    // ---- phase 1: read a1; stage B.h0(t+2); MFMA (m0,n23)
#pragma unroll
    for (int mf = 0; mf < 4; ++mf) {
      const int rowi = wrow * 128 + 64 + mf * 16 + lo;
#pragma unroll
      for (int kk = 0; kk < 2; ++kk)
        a1[mf][kk] = *(const bf16x8*)&Ab_[rowi * 64 + ((kk * 32 + g * 8) ^ swz)];
    }
    if (t + 2 < NT)
      ST2(pB0, pB1, sm + (t & 1) * 32768 + 16384);
    __builtin_amdgcn_s_barrier();
    __builtin_amdgcn_s_setprio(1);
#pragma unroll
    for (int mf = 0; mf < 4; ++mf)
#pragma unroll
      for (int nf = 2; nf < 4; ++nf)
#pragma unroll
        for (int kk = 0; kk < 2; ++kk)
          acc[mf][nf] = __builtin_amdgcn_mfma_f32_16x16x32_bf16(a0[mf][kk], bfr[nf][kk], acc[mf][nf], 0, 0, 0);
    __builtin_amdgcn_s_setprio(0);
    __builtin_amdgcn_s_barrier();
    // ---- phase 2: stage B.h1(t+2); MFMA (m1,n01)
    if (t + 2 < NT)
      ST2(pB2, pB3, sm + (t & 1) * 32768 + 16384 + 8192);
    __builtin_amdgcn_s_barrier();
    __builtin_amdgcn_s_setprio(1);
#pragma unroll
    for (int mf = 0; mf < 4; ++mf)
#pragma unroll
      for (int nf = 0; nf < 2; ++nf)
#pragma unroll
        for (int kk = 0; kk < 2; ++kk)
          acc[4 + mf][nf] = __builtin_amdgcn_mfma_f32_16x16x32_bf16(a1[mf][kk], bfr[nf][kk], acc[4 + mf][nf], 0, 0, 0);
    __builtin_amdgcn_s_setprio(0);
    __builtin_amdgcn_s_barrier();
    // ---- phase 3: stage A.h0(t+2); MFMA (m1,n23); counted vmcnt (0 at tail)
    if (t + 2 < NT)
      ST2(pA0, pA1, sm + (t & 1) * 32768);
    __builtin_amdgcn_s_barrier();
    __builtin_amdgcn_s_setprio(1);
#pragma unroll
    for (int mf = 0; mf < 4; ++mf)
#pragma unroll
      for (int nf = 2; nf < 4; ++nf)
#pragma unroll
        for (int kk = 0; kk < 2; ++kk)
          acc[4 + mf][nf] = __builtin_amdgcn_mfma_f32_16x16x32_bf16(a1[mf][kk], bfr[nf][kk], acc[4 + mf][nf], 0, 0, 0);
    __builtin_amdgcn_s_setprio(0);
    if (t + 2 < NT) asm volatile("s_waitcnt vmcnt(6)" ::: "memory");
    else            asm volatile("s_waitcnt vmcnt(0)" ::: "memory");
    __builtin_amdgcn_s_barrier();
  }

  if (MODE == 1) {
    // register-paired GEGLU: acc[mi][2s]=h1, acc[mi][2s+1]=h2, same out col.
    const int obase = bn >> 1;
#pragma unroll
    for (int mi = 0; mi < 8; ++mi) {
#pragma unroll
      for (int sub = 0; sub < 2; ++sub) {
        const int col = obase + wcol * 32 + sub * 16 + lo;
        const float b1 = bias[col];
        const float b2 = bias[4096 + col];
#pragma unroll
        for (int rr = 0; rr < 4; ++rr) {
          const int rowi = wrow * 128 + mi * 16 + g * 4 + rr;
          const float h1 = acc[mi][sub * 2][rr] + b1;
          const float h2 = acc[mi][sub * 2 + 1][rr] + b2;
          const float ge = 0.5f * h2 * (1.0f + erff(h2 * 0.70710678118f));
          outB[(size_t)(bm + rowi) * 4096 + col] = f2bf(h1 * ge);
        }
      }
    }
    return;
  }

#pragma unroll
  for (int mi = 0; mi < 8; ++mi) {
#pragma unroll
    for (int ni = 0; ni < 4; ++ni) {
      const int col = bn + wcol * 64 + ni * 16 + lo;
      const float bb = bias ? bias[col] : 0.0f;
      const int row0 = bm + wrow * 128 + mi * 16 + g * 4;
#pragma unroll
      for (int rr = 0; rr < 4; ++rr) {
        const size_t off = (size_t)(row0 + rr) * N + col;
        float v = acc[mi][ni][rr] * oscale + bb;
        if (resid) v += resid[off];
        if (outF) outF[off] = v;
        else outB[off] = f2bf(v);
      }
    }
  }
}

// ---------------- fused flash attention v6: QK-ahead pipeline, unroll-2 loop
// (static buffers per parity, no state copies), running staging pointers,
// MFMA row-sum lsum + defer-max (THR=8, base-2).
#define ABODY(TT, KST, KRD, VST, VRD, SCur, SNxt)                                  \
  {                                                                                \
    if ((TT) + 2 < ntile) {                                                        \
      gld16(kp0, &KST[tid * 8]);                                                   \
      gld16(kp1, &KST[2048 + tid * 8]);                                            \
      kp0 += kadv; kp1 += kadv;                                                    \
    }                                                                              \
    if ((TT) + 1 < ntile) {                                                        \
      gld16(vp0, &VST[tid * 8]);                                                   \
      gld16(vp1, &VST[2048 + tid * 8]);                                            \
      vp0 += 64; vp1 += 64;                                                        \
    }                                                                              \
    if ((TT) + 2 < ntile)      asm volatile("s_waitcnt vmcnt(4)" ::: "memory");    \
    else if ((TT) + 1 < ntile) asm volatile("s_waitcnt vmcnt(2)" ::: "memory");    \
    else                       asm volatile("s_waitcnt vmcnt(0)" ::: "memory");    \
    __builtin_amdgcn_s_barrier();                                                  \
    if ((TT) + 1 < ntile) {                                                        \
      _Pragma("unroll")                                                            \
      for (int c = 0; c < 4; ++c) {                                                \
        f32x4 zz = {};                                                             \
        SNxt[c] = zz;                                                              \
        _Pragma("unroll")                                                          \
        for (int kk = 0; kk < 2; ++kk) {                                           \
          bf16x8 kf = *(const bf16x8*)&KRD[(c * 16 + lo) * 64 +                    \
                                           ((kk * 32 + g * 8) ^ ((lo & 7) << 3))]; \
          SNxt[c] = __builtin_amdgcn_mfma_f32_16x16x32_bf16(kf, qf[kk], SNxt[c], 0, 0, 0); \
        }                                                                          \
      }                                                                            \
    }                                                                              \
    float mx = fmaxf(fmaxf(fmaxf(SCur[0][0], SCur[0][1]), fmaxf(SCur[0][2], SCur[0][3])),  \
                     fmaxf(fmaxf(SCur[1][0], SCur[1][1]), fmaxf(SCur[1][2], SCur[1][3]))); \
    mx = fmaxf(mx, fmaxf(fmaxf(fmaxf(SCur[2][0], SCur[2][1]), fmaxf(SCur[2][2], SCur[2][3])),  \
                         fmaxf(fmaxf(SCur[3][0], SCur[3][1]), fmaxf(SCur[3][2], SCur[3][3])))); \
    mx = fmaxf(mx, __shfl_xor(mx, 16));                                            \
    mx = fmaxf(mx, __shfl_xor(mx, 32));                                            \
    if (!__all(mx <= m + 8.0f)) {                                                  \
      const float mn = fmaxf(m, mx);                                               \
      const float al = exp2f(m - mn);                                              \
      m = mn;                                                                      \
      f32x4 arv;                                                                   \
      _Pragma("unroll")                                                            \
      for (int rr = 0; rr < 4; ++rr) arv[rr] = __shfl(al, 20 * g + rr);            \
      _Pragma("unroll")                                                            \
      for (int dn = 0; dn < 4; ++dn) oa[dn] *= arv;                                \
      lrow *= arv;                                                                 \
    }                                                                              \
    _Pragma("unroll")                                                              \
    for (int c = 0; c < 4; ++c)                                                    \
      _Pragma("unroll")                                                            \
      for (int rr = 0; rr < 4; ++rr)                                               \
        SCur[c][rr] = exp2f(SCur[c][rr] - m);                                      \
    union { uint32_t u[4]; bf16x8 v; } af[2];                                      \
    _Pragma("unroll")                                                              \
    for (int ks = 0; ks < 2; ++ks) {                                               \
      af[ks].u[0] = cvtpk(SCur[2 * ks][0], SCur[2 * ks][1]);                       \
      af[ks].u[1] = cvtpk(SCur[2 * ks][2], SCur[2 * ks][3]);                       \
      af[ks].u[2] = cvtpk(SCur[2 * ks + 1][0], SCur[2 * ks + 1][1]);               \
      af[ks].u[3] = cvtpk(SCur[2 * ks + 1][2], SCur[2 * ks + 1][3]);               \
    }                                                                              \
    lrow = __builtin_amdgcn_mfma_f32_16x16x32_bf16(af[0].v, onesc.v, lrow, 0, 0, 0); \
    lrow = __builtin_amdgcn_mfma_f32_16x16x32_bf16(af[1].v, onesc.v, lrow, 0, 0, 0); \
    _Pragma("unroll")                                                              \
    for (int dn = 0; dn < 4; ++dn)                                                 \
      _Pragma("unroll")                                                            \
      for (int ks = 0; ks < 2; ++ks) {                                             \
        bf16x8 vf = *(const bf16x8*)&VRD[(dn * 16 + lo) * 64 +                     \
                                         ((ks * 32 + g * 8) ^ ((lo & 7) << 3))];   \
        oa[dn] = __builtin_amdgcn_mfma_f32_16x16x32_bf16(af[ks].v, vf, oa[dn], 0, 0, 0); \
      }                                                                            \
    asm volatile("s_waitcnt lgkmcnt(0)" ::: "memory");                             \
    __builtin_amdgcn_s_barrier();                                                  \
  }

__global__ __launch_bounds__(256, 4)
void attn_fwd(const u16* __restrict__ Q, int ldq, const u16* __restrict__ K, int ldk,
              const u16* __restrict__ Vt, u16* __restrict__ O, int T, int S) {
  __shared__ __align__(16) u16 Kl[2][4096];
  __shared__ __align__(16) u16 Vl[2][4096];
  const int tid = threadIdx.x, w = tid >> 6, l = tid & 63, lo = l & 15, g = l >> 4;
  const int nwg = gridDim.x * gridDim.y;
  const int n = blockIdx.y * gridDim.x + blockIdx.x;
  const int sid = (n & 7) * (nwg >> 3) + (n >> 3);
  const int qt = sid % gridDim.x, bh = sid / gridDim.x;
  const int b = bh >> 4, h = bh & 15, hc = h * 64;
  const int q0 = qt * 64 + w * 16;
  const size_t qrow = (size_t)b * T + q0;
  const size_t krow0 = (size_t)b * S;
  const size_t vrow0 = (size_t)bh * 64;

  bf16x8 qf[2];
#pragma unroll
  for (int kk = 0; kk < 2; ++kk)
    qf[kk] = *(const bf16x8*)&Q[(qrow + lo) * ldq + hc + kk * 32 + g * 8];

  // all-ones bf16 fragment for MFMA row-sum
  union { u16 u[8]; bf16x8 v; } onesc;
#pragma unroll
  for (int j = 0; j < 8; ++j) onesc.u[j] = 0x3F80;

  f32x4 oa[4] = {};
  f32x4 lrow = {};
  float m = -1e30f;

  const int srow = tid >> 3;
  const int scol = (((tid & 7) ^ (srow & 7)) << 3);
  const int ntile = S >> 6;
  const size_t kadv = (size_t)64 * ldk;

  // running staging pointers: next K tile = 2, next V tile = 1 (after prologue)
  const u16* kp0 = K + (krow0 + 128 + srow) * ldk + hc + scol;
  const u16* kp1 = K + (krow0 + 160 + srow) * ldk + hc + scol;
  const u16* vp0 = Vt + (vrow0 + srow) * S + 64 + scol;
  const u16* vp1 = Vt + (vrow0 + 32 + srow) * S + 64 + scol;

  // prologue: K(0)->Kl[0], K(1)->Kl[1], V(0)->Vl[0]; then QK(0)->sC
#pragma unroll
  for (int c = 0; c < 2; ++c)
    gld16(K + (krow0 + c * 32 + srow) * ldk + hc + scol, &Kl[0][c * 2048 + tid * 8]);
#pragma unroll
  for (int c = 0; c < 2; ++c)
    gld16(K + (krow0 + 64 + c * 32 + srow) * ldk + hc + scol, &Kl[1][c * 2048 + tid * 8]);
#pragma unroll
  for (int c = 0; c < 2; ++c)
    gld16(Vt + (vrow0 + c * 32 + srow) * S + scol, &Vl[0][c * 2048 + tid * 8]);
  asm volatile("s_waitcnt vmcnt(0)" ::: "memory");
  __builtin_amdgcn_s_barrier();

  f32x4 sC[4] = {}, sN[4] = {};
#pragma unroll
  for (int c = 0; c < 4; ++c)
#pragma unroll
    for (int kk = 0; kk < 2; ++kk) {
      bf16x8 kf = *(const bf16x8*)&Kl[0][(c * 16 + lo) * 64 +
                                        ((kk * 32 + g * 8) ^ ((lo & 7) << 3))];
      sC[c] = __builtin_amdgcn_mfma_f32_16x16x32_bf16(kf, qf[kk], sC[c], 0, 0, 0);
    }
  asm volatile("s_waitcnt lgkmcnt(0)" ::: "memory");
  __builtin_amdgcn_s_barrier();

  for (int t0 = 0; t0 < ntile; t0 += 2) {
    ABODY(t0,     Kl[0], Kl[1], Vl[1], Vl[0], sC, sN)
    ABODY(t0 + 1, Kl[1], Kl[0], Vl[0], Vl[1], sN, sC)
  }

#pragma unroll
  for (int dn = 0; dn < 4; ++dn)
#pragma unroll
    for (int rr = 0; rr < 4; ++rr)
      O[(qrow + g * 4 + rr) * 1024 + hc + dn * 16 + lo] = f2bf(oa[dn][rr] / lrow[rr]);
}

extern "C" void kernel_launch(void* const* d_in, const int* in_sizes, int n_in,
                              void* d_out, int out_size, void* d_ws, size_t ws_size,
                              hipStream_t stream) {
  const float* x      = (const float*)d_in[0];
  const float* enc    = (const float*)d_in[1];
  const float* ln1_w  = (const float*)d_in[2];
  const float* ln1_b  = (const float*)d_in[3];
  const float* a1_wq  = (const float*)d_in[4];
  const float* a1_wk  = (const float*)d_in[5];
  const float* a1_wv  = (const float*)d_in[6];
  const float* a1_wo  = (const float*)d_in[7];
  const float* a1_bo  = (const float*)d_in[8];
  const float* ln2_w  = (const float*)d_in[9];
  const float* ln2_b  = (const float*)d_in[10];
  const float* a2_wq  = (const float*)d_in[11];
  const float* a2_wk  = (const float*)d_in[12];
  const float* a2_wv  = (const float*)d_in[13];
  const float* a2_wo  = (const float*)d_in[14];
  const float* a2_bo  = (const float*)d_in[15];
  const float* ln3_w  = (const float*)d_in[16];
  const float* ln3_b  = (const float*)d_in[17];
  const float* ff_w1  = (const float*)d_in[18];
  const float* ff_b1  = (const float*)d_in[19];
  const float* ff_w2  = (const float*)d_in[20];
  const float* ff_b2  = (const float*)d_in[21];

  char* ws = (char*)d_ws;
  const size_t MB = 1u << 20;
  u16* wqkv1t = (u16*)(ws + 0 * MB);              // 3072x1024 = 6 MB
  u16* wo1t   = (u16*)(ws + 6 * MB);
  u16* wq2t   = (u16*)(ws + 8 * MB);
  u16* wo2t   = (u16*)(ws + 10 * MB);
  u16* wkv2t  = (u16*)(ws + 12 * MB);             // 2048x64 = 256 KB
  u16* encb   = (u16*)(ws + 12 * MB + 512 * 1024);
  u16* w1t    = (u16*)(ws + 13 * MB);             // 16 MB (geglu-paired)
  u16* w2t    = (u16*)(ws + 29 * MB);             // 8 MB
  float* x2   = (float*)(ws + 37 * MB);           // 16 MB (live from wo2 on)
  u16* Vt1    = (u16*)(ws + 37 * MB);             // 8 MB (dead before wo2)
  u16* Vt2    = (u16*)(ws + 45 * MB);             // 2 MB (dead before wo2)
  u16* KVb    = (u16*)(ws + 47 * MB);             // 1024x2048 = 4 MB
  u16* hbuf   = (u16*)(ws + 53 * MB);             // 8 MB
  u16* qkv    = (u16*)(ws + 61 * MB);             // 24 MB
  u16* Qb     = (u16*)(ws + 61 * MB);             // cross-attn reuse
  u16* Ab     = (u16*)(ws + 85 * MB);             // 8 MB
  float* x1   = (float*)(ws + 93 * MB);           // 16 MB -> 109
  u16* gq     = (u16*)(ws + 61 * MB);             // 4096x4096 = 32 MB (reuses qkv/Ab)

  const float SCL = 0.125f * 1.44269504f;
  const dim3 tb(32, 8);
  {
    WB wb;
    wb.src[0] = a1_wq; wb.dst[0] = wqkv1t;               wb.scale[0] = SCL;
    wb.src[1] = a1_wk; wb.dst[1] = wqkv1t + 1024 * 1024; wb.scale[1] = 1.0f;
    wb.src[2] = a1_wv; wb.dst[2] = wqkv1t + 2048 * 1024; wb.scale[2] = 1.0f;
    wb.src[3] = a1_wo; wb.dst[3] = wo1t;                 wb.scale[3] = 1.0f;
    wb.src[4] = a2_wq; wb.dst[4] = wq2t;                 wb.scale[4] = SCL;
    wb.src[5] = a2_wo; wb.dst[5] = wo2t;                 wb.scale[5] = 1.0f;
    wconv_b<<<dim3(32, 32, 6), tb, 0, stream>>>(wb, 1024, 1024);
    WB wb2;
    wb2.src[0] = a2_wk; wb2.dst[0] = wkv2t;             wb2.scale[0] = 1.0f;
    wb2.src[1] = a2_wv; wb2.dst[1] = wkv2t + 64 * 1024; wb2.scale[1] = 1.0f;
    wb2.src[2] = a2_wk; wb2.dst[2] = wkv2t;             wb2.scale[2] = 1.0f;
    wb2.src[3] = a2_wk; wb2.dst[3] = wkv2t;             wb2.scale[3] = 1.0f;
    wb2.src[4] = a2_wk; wb2.dst[4] = wkv2t;             wb2.scale[4] = 1.0f;
    wb2.src[5] = a2_wk; wb2.dst[5] = wkv2t;             wb2.scale[5] = 1.0f;
    wconv_b<<<dim3(32, 2, 2), tb, 0, stream>>>(wb2, 64, 1024);
  }
  wconv_g<<<dim3(256, 32), tb, 0, stream>>>(ff_w1, w1t);
  wconv_t<<<dim3(32, 128), tb, 0, stream>>>(ff_w2, w2t, 4096, 1024);
  cvt_bf<<<256, 256, 0, stream>>>(enc, encb, 2 * 512 * 64);

  // ---- self-attention sub-block
  ln_fwd<<<4096, 256, 0, stream>>>(x, ln1_w, ln1_b, hbuf);
  gemm256<0><<<dim3(16, 12), 512, 0, stream>>>(hbuf, 1024, wqkv1t, 4096, 3072, 1024, nullptr, nullptr, 1.0f, nullptr, qkv);
  vtrans<<<dim3(32, 32), 256, 0, stream>>>(qkv, 3072, 2048, Vt1, 2048);
  attn_fwd<<<dim3(32, 32), 256, 0, stream>>>(qkv, 3072, qkv + 1024, 3072, Vt1, Ab, 2048, 2048);
  gemm_bf16<64><<<dim3(32, 16), 256, 0, stream>>>(Ab, 1024, wo1t, 4096, 1024, 1024, a1_bo, x, 1.0f, x1, nullptr);

  // ---- cross-attention sub-block
  ln_fwd<<<4096, 256, 0, stream>>>(x1, ln2_w, ln2_b, hbuf);
  gemm_bf16<64><<<dim3(32, 16), 256, 0, stream>>>(hbuf, 1024, wq2t, 4096, 1024, 1024, nullptr, nullptr, 1.0f, nullptr, Qb);
  gemm_bf16<64><<<dim3(8, 32), 256, 0, stream>>>(encb, 64, wkv2t, 1024, 2048, 64, nullptr, nullptr, 1.0f, nullptr, KVb);
  vtrans<<<dim3(8, 32), 256, 0, stream>>>(KVb + 1024, 2048, 0, Vt2, 512);
  attn_fwd<<<dim3(32, 32), 256, 0, stream>>>(Qb, 1024, KVb, 2048, Vt2, Ab, 2048, 512);
  gemm_bf16<64><<<dim3(32, 16), 256, 0, stream>>>(Ab, 1024, wo2t, 4096, 1024, 1024, a2_bo, x1, 1.0f, x2, nullptr);

  // ---- GEGLU feed-forward sub-block (geglu fused into FF1 epilogue)
  ln_fwd<<<4096, 256, 0, stream>>>(x2, ln3_w, ln3_b, hbuf);
  gemm256<1><<<dim3(16, 32), 512, 0, stream>>>(hbuf, 1024, w1t, 4096, 8192, 1024, ff_b1, nullptr, 1.0f, nullptr, gq);
  gemm_bf16<64><<<dim3(32, 16), 256, 0, stream>>>(gq, 4096, w2t, 4096, 1024, 4096, ff_b2, x2, 1.0f, (float*)d_out, nullptr);
}

// Round 12
// 397.662 us; speedup vs baseline: 1.0810x; 1.0304x over previous
//
#include <hip/hip_runtime.h>
#include <hip/hip_bf16.h>
#include <stdint.h>

typedef unsigned short u16;
typedef __bf16 bf16x8 __attribute__((ext_vector_type(8)));
typedef float f32x4 __attribute__((ext_vector_type(4)));
typedef u16 u16x8 __attribute__((ext_vector_type(8)));
typedef u16 u16x4 __attribute__((ext_vector_type(4)));

__device__ __forceinline__ u16 f2bf(float f) {
  union { float f; uint32_t u; } v; v.f = f;
  uint32_t r = v.u + 0x7fffu + ((v.u >> 16) & 1u);
  return (u16)(r >> 16);
}
__device__ __forceinline__ float bf2f(u16 u) {
  union { uint32_t u; float f; } v; v.u = ((uint32_t)u) << 16;
  return v.f;
}
__device__ __forceinline__ uint32_t cvtpk(float a, float b) {
  uint32_t r;
  asm("v_cvt_pk_bf16_f32 %0, %1, %2" : "=v"(r) : "v"(a), "v"(b));
  return r;
}

// async global->LDS, 16B per lane. LDS dest must be linear (base + lane*16).
__device__ __forceinline__ void gld16(const u16* g, u16* l) {
  __builtin_amdgcn_global_load_lds(
      (const __attribute__((address_space(1))) uint32_t*)g,
      (__attribute__((address_space(3))) uint32_t*)l, 16, 0, 0);
}

// ---------------- batched weight convert+transpose: W (K x N, f32) -> Wt (N x K, bf16)
struct WB {
  const float* src[6];
  u16* dst[6];
  float scale[6];
};
__global__ void wconv_b(WB wb, int K, int N) {
  const int z = blockIdx.z;
  const float* __restrict__ W = wb.src[z];
  u16* __restrict__ Wt = wb.dst[z];
  const float scale = wb.scale[z];
  __shared__ float tile[32][33];
  const int n0 = blockIdx.x * 32, k0 = blockIdx.y * 32;
  const int tx = threadIdx.x, ty = threadIdx.y;   // (32, 8)
#pragma unroll
  for (int i = 0; i < 4; ++i)
    tile[ty + 8 * i][tx] = W[(size_t)(k0 + ty + 8 * i) * N + n0 + tx];
  __syncthreads();
#pragma unroll
  for (int i = 0; i < 4; ++i)
    Wt[(size_t)(n0 + ty + 8 * i) * K + k0 + tx] = f2bf(scale * tile[tx][ty + 8 * i]);
}

// plain single-matrix variant (ff_w2)
__global__ void wconv_t(const float* __restrict__ W, u16* __restrict__ Wt, int K, int N) {
  __shared__ float tile[32][33];
  const int n0 = blockIdx.x * 32, k0 = blockIdx.y * 32;
  const int tx = threadIdx.x, ty = threadIdx.y;
#pragma unroll
  for (int i = 0; i < 4; ++i)
    tile[ty + 8 * i][tx] = W[(size_t)(k0 + ty + 8 * i) * N + n0 + tx];
  __syncthreads();
#pragma unroll
  for (int i = 0; i < 4; ++i)
    Wt[(size_t)(n0 + ty + 8 * i) * K + k0 + tx] = f2bf(tile[tx][ty + 8 * i]);
}

// ff_w1 convert with fragment-paired GEGLU rows:
// orig col n = half*4096 + blk*128 + wcol*32 + sub*16 + idx
// -> dst row p = blk*256 + wcol*64 + (sub*2+half)*16 + idx
__global__ void wconv_g(const float* __restrict__ W, u16* __restrict__ Wt) {
  __shared__ float tile[32][33];
  const int n0 = blockIdx.x * 32, k0 = blockIdx.y * 32;
  const int tx = threadIdx.x, ty = threadIdx.y;
#pragma unroll
  for (int i = 0; i < 4; ++i)
    tile[ty + 8 * i][tx] = W[(size_t)(k0 + ty + 8 * i) * 8192 + n0 + tx];
  __syncthreads();
#pragma unroll
  for (int i = 0; i < 4; ++i) {
    const int n = n0 + ty + 8 * i;
    const int half = n >> 12, c = n & 4095;
    const int blk = c >> 7, cc = c & 127;
    const int wcol = cc >> 5, rem = cc & 31;
    const int sub = rem >> 4, idx = rem & 15;
    const int p = blk * 256 + wcol * 64 + (sub * 2 + half) * 16 + idx;
    Wt[(size_t)p * 1024 + k0 + tx] = f2bf(tile[tx][ty + 8 * i]);
  }
}

// ---------------- simple f32 -> bf16 convert (encoder states)
__global__ void cvt_bf(const float* __restrict__ in, u16* __restrict__ out, int n) {
  int i = blockIdx.x * 256 + threadIdx.x;
  if (i < n) out[i] = f2bf(in[i]);
}

// ---------------- V transpose pre-pass: V rows (s) -> Vt[(bh*64+d)*S + t0*64 + pos(s)]
__global__ __launch_bounds__(256)
void vtrans(const u16* __restrict__ V, int ldv, int hoff, u16* __restrict__ Vt, int S) {
  __shared__ u16 tile[64][72];
  const int t0 = blockIdx.x, bh = blockIdx.y;
  const int b = bh >> 4, hc = (bh & 15) * 64 + hoff;
  const int tid = threadIdx.x;
  const int r = tid >> 2, dq = (tid & 3) * 16;
  const int pos = ((r >> 5) << 5) | (((r >> 2) & 3) << 3) | (((r >> 4) & 1) << 2) | (r & 3);
  const size_t grow = ((size_t)b * S + t0 * 64 + r) * ldv + hc + dq;
  u16x8 v1 = *(const u16x8*)&V[grow];
  u16x8 v2 = *(const u16x8*)&V[grow + 8];
#pragma unroll
  for (int j = 0; j < 8; ++j) {
    tile[dq + j][pos] = v1[j];
    tile[dq + 8 + j][pos] = v2[j];
  }
  __syncthreads();
  const int d = tid >> 2, c = (tid & 3) * 16;
  u16x8 o1, o2;
#pragma unroll
  for (int j = 0; j < 8; ++j) { o1[j] = tile[d][c + j]; o2[j] = tile[d][c + 8 + j]; }
  *(u16x8*)&Vt[((size_t)bh * 64 + d) * S + t0 * 64 + c] = o1;
  *(u16x8*)&Vt[((size_t)bh * 64 + d) * S + t0 * 64 + c + 8] = o2;
}

// ---------------- LayerNorm: row of 1024 f32 -> bf16
__global__ __launch_bounds__(256)
void ln_fwd(const float* __restrict__ X, const float* __restrict__ wt,
            const float* __restrict__ bs, u16* __restrict__ Y) {
  const int row = blockIdx.x, t = threadIdx.x;
  const float4 v = *(const float4*)&X[(size_t)row * 1024 + t * 4];
  float s = v.x + v.y + v.z + v.w;
  float s2 = v.x * v.x + v.y * v.y + v.z * v.z + v.w * v.w;
#pragma unroll
  for (int off = 32; off > 0; off >>= 1) {
    s += __shfl_xor(s, off);
    s2 += __shfl_xor(s2, off);
  }
  __shared__ float rs[4], rs2[4];
  const int w = t >> 6;
  if ((t & 63) == 0) { rs[w] = s; rs2[w] = s2; }
  __syncthreads();
  s = rs[0] + rs[1] + rs[2] + rs[3];
  s2 = rs2[0] + rs2[1] + rs2[2] + rs2[3];
  const float mu = s * (1.0f / 1024.0f);
  const float var = s2 * (1.0f / 1024.0f) - mu * mu;
  const float rstd = rsqrtf(var + 1e-5f);
  const float4 wv = *(const float4*)&wt[t * 4];
  const float4 bv = *(const float4*)&bs[t * 4];
  u16x4 o;
  o[0] = f2bf((v.x - mu) * rstd * wv.x + bv.x);
  o[1] = f2bf((v.y - mu) * rstd * wv.y + bv.y);
  o[2] = f2bf((v.z - mu) * rstd * wv.z + bv.z);
  o[3] = f2bf((v.w - mu) * rstd * wv.w + bv.w);
  *(u16x4*)&Y[(size_t)row * 1024 + t * 4] = o;
}

// stage K-tile kt of A(128x64) + B(TNx64) into buffer bufi (swizzled source)
#define GSTAGE(kt, bufi)                                                         \
  {                                                                              \
    _Pragma("unroll")                                                            \
    for (int p = 0; p < 4; ++p) {                                                \
      int idx = p * 256 + tid;                                                   \
      int row = idx >> 3, c = idx & 7;                                           \
      gld16(A + (size_t)(bm + row) * lda + (kt) * 64 + ((c ^ (row & 7)) << 3),   \
            &Al[bufi][idx * 8]);                                                 \
    }                                                                            \
    _Pragma("unroll")                                                            \
    for (int p = 0; p < TN / 32; ++p) {                                          \
      int idx = p * 256 + tid;                                                   \
      int row = idx >> 3, c = idx & 7;                                           \
      gld16(Bt + (size_t)(bn + row) * K + (kt) * 64 + ((c ^ (row & 7)) << 3),    \
            &Bl[bufi][idx * 8]);                                                 \
    }                                                                            \
  }

// ---------------- 128xTN pipelined GEMM (N=1024-class shapes), XCD- + T2-swizzled
// minimum-2-phase double-buffer: STAGE(t+1) issued BEFORE compute(t), single
// vmcnt(0)+barrier at iteration end (loads fly under the MFMAs).
template<int TN>
__global__ __launch_bounds__(256, 3)
void gemm_bf16(const u16* __restrict__ A, int lda, const u16* __restrict__ Bt,
               int M, int N, int K, const float* __restrict__ bias,
               const float* __restrict__ resid, float oscale,
               float* __restrict__ outF, u16* __restrict__ outB) {
  constexpr int WNV = (TN == 128) ? 2 : 1;
  constexpr int WMV = 4 / WNV;
  constexpr int WM = 128 / WMV;
  constexpr int WN = TN / WNV;
  constexpr int MI = WM / 16, NI = WN / 16;
  __shared__ __align__(16) u16 Al[2][128 * 64];
  __shared__ __align__(16) u16 Bl[2][TN * 64];
  const int tid = threadIdx.x;
  const int w = tid >> 6, l = tid & 63, lo = l & 15, g = l >> 4;
  const int gx = gridDim.x, nwg = gx * gridDim.y;
  const int lin = blockIdx.y * gx + blockIdx.x;
  const int q = nwg >> 3, r = nwg & 7;
  const int xcd = lin & 7, pos = lin >> 3;
  const int sid = (xcd < r ? xcd * (q + 1) : r * (q + 1) + (xcd - r) * q) + pos;
  const int bm = (sid % gx) * 128, bn = (sid / gx) * TN;
  const int wm = (w / WNV) * WM, wn = (w % WNV) * WN;
  const int swz = (lo & 7) << 3;
  const int NT = K >> 6;
  f32x4 acc[MI][NI] = {};

  GSTAGE(0, 0);
  asm volatile("s_waitcnt vmcnt(0)" ::: "memory");
  __syncthreads();

  for (int t = 0; t < NT; ++t) {
    const int cur = t & 1;
    if (t + 1 < NT) GSTAGE(t + 1, cur ^ 1);
#pragma unroll
    for (int ks = 0; ks < 2; ++ks) {
      bf16x8 af[MI], bf[NI];
#pragma unroll
      for (int i = 0; i < MI; ++i)
        af[i] = *(const bf16x8*)&Al[cur][(wm + i * 16 + lo) * 64 + ((ks * 32 + g * 8) ^ swz)];
#pragma unroll
      for (int i = 0; i < NI; ++i)
        bf[i] = *(const bf16x8*)&Bl[cur][(wn + i * 16 + lo) * 64 + ((ks * 32 + g * 8) ^ swz)];
#pragma unroll
      for (int mi = 0; mi < MI; ++mi)
#pragma unroll
        for (int ni = 0; ni < NI; ++ni)
          acc[mi][ni] = __builtin_amdgcn_mfma_f32_16x16x32_bf16(af[mi], bf[ni], acc[mi][ni], 0, 0, 0);
    }
    asm volatile("s_waitcnt vmcnt(0)" ::: "memory");
    __syncthreads();
  }

#pragma unroll
  for (int mi = 0; mi < MI; ++mi) {
#pragma unroll
    for (int ni = 0; ni < NI; ++ni) {
      const int col = bn + wn + ni * 16 + lo;
      const float bb = bias ? bias[col] : 0.0f;
      const int row0 = bm + wm + mi * 16 + g * 4;
#pragma unroll
      for (int rr = 0; rr < 4; ++rr) {
        const size_t off = (size_t)(row0 + rr) * N + col;
        float v = acc[mi][ni][rr] * oscale + bb;
        if (resid) v += resid[off];
        if (outF) outF[off] = v;
        else outB[off] = f2bf(v);
      }
    }
  }
}

// stage one 128x64 half-tile from two running per-thread pointers (advance +64/tile)
#define ST2(p0, p1, dst) { gld16(p0, (dst) + tid * 8); gld16(p1, (dst) + 4096 + tid * 8); (p0) += 64; (p1) += 64; }

// ---------------- 256x256 8-phase GEMM; running staging pointers, counted vmcnt
// MODE 0: normal epilogue. MODE 1: register-paired GEGLU epilogue:
// acc[mi][2s] = h1, acc[mi][2s+1] = h2 for the SAME output col; out = h1*gelu(h2).
template<int MODE>
__global__ __launch_bounds__(512, 2)
void gemm256(const u16* __restrict__ A, int lda, const u16* __restrict__ Bt,
             int M, int N, int K, const float* __restrict__ bias,
             const float* __restrict__ resid, float oscale,
             float* __restrict__ outF, u16* __restrict__ outB) {
  __shared__ __align__(16) u16 sm[65536];   // [2 dbuf][A 16384 | B 16384] u16
  const int tid = threadIdx.x;
  const int w = tid >> 6, l = tid & 63, lo = l & 15, g = l >> 4;
  const int wrow = w >> 2, wcol = w & 3;
  const int gx = gridDim.x;
  const int nwg = gx * gridDim.y;
  const int lin = blockIdx.y * gx + blockIdx.x;
  const int q = nwg >> 3, r = nwg & 7;
  const int xcd = lin & 7, pos = lin >> 3;
  const int sid = (xcd < r ? xcd * (q + 1) : r * (q + 1) + (xcd - r) * q) + pos;
  const int bm = (sid % gx) * 256, bn = (sid / gx) * 256;

  const int NT = K >> 6;
  const int swz = (lo & 7) << 3;
  f32x4 acc[8][4] = {};

  // per-thread running staging pointers (strength-reduced addresses)
  const int sr8 = tid >> 3;
  const int sc8 = ((tid & 7) ^ (sr8 & 7)) << 3;
  const u16 *pA0 = A + (size_t)(bm + sr8) * lda + sc8;
  const u16 *pA1 = A + (size_t)(bm + 64 + sr8) * lda + sc8;
  const u16 *pA2 = A + (size_t)(bm + 128 + sr8) * lda + sc8;
  const u16 *pA3 = A + (size_t)(bm + 192 + sr8) * lda + sc8;
  const u16 *pB0 = Bt + (size_t)(bn + sr8) * K + sc8;
  const u16 *pB1 = Bt + (size_t)(bn + 64 + sr8) * K + sc8;
  const u16 *pB2 = Bt + (size_t)(bn + 128 + sr8) * K + sc8;
  const u16 *pB3 = Bt + (size_t)(bn + 192 + sr8) * K + sc8;

  // prologue (same stage order as before)
  ST2(pB0, pB1, sm + 16384);
  ST2(pB2, pB3, sm + 16384 + 8192);
  ST2(pA0, pA1, sm);
  ST2(pA2, pA3, sm + 8192);
  if (NT > 1) {
    ST2(pB0, pB1, sm + 32768 + 16384);
    ST2(pB2, pB3, sm + 32768 + 16384 + 8192);
    ST2(pA0, pA1, sm + 32768);
  }
  asm volatile("s_waitcnt vmcnt(6)" ::: "memory");
  __builtin_amdgcn_s_barrier();

  for (int t = 0; t < NT; ++t) {
    u16* Ab_ = sm + (t & 1) * 32768;
    u16* Bb_ = Ab_ + 16384;
    bf16x8 a0[4][2], a1[4][2], bfr[4][2];
    // ---- phase 0: read a0 + all B; stage A.h1(t+1); MFMA (m0,n01)
#pragma unroll
    for (int mf = 0; mf < 4; ++mf) {
      const int rowi = wrow * 128 + mf * 16 + lo;
#pragma unroll
      for (int kk = 0; kk < 2; ++kk)
        a0[mf][kk] = *(const bf16x8*)&Ab_[rowi * 64 + ((kk * 32 + g * 8) ^ swz)];
    }
#pragma unroll
    for (int nf = 0; nf < 4; ++nf) {
      const int rowi = wcol * 64 + nf * 16 + lo;
#pragma unroll
      for (int kk = 0; kk < 2; ++kk)
        bfr[nf][kk] = *(const bf16x8*)&Bb_[rowi * 64 + ((kk * 32 + g * 8) ^ swz)];
    }
    if (t + 1 < NT)
      ST2(pA2, pA3, sm + ((t + 1) & 1) * 32768 + 8192);
    __builtin_amdgcn_s_barrier();
    __builtin_amdgcn_s_setprio(1);
#pragma unroll
    for (int mf = 0; mf < 4; ++mf)
#pragma unroll
      for (int nf = 0; nf < 2; ++nf)
#pragma unroll
        for (int kk = 0; kk < 2; ++kk)
          acc[mf][nf] = __builtin_amdgcn_mfma_f32_16x16x32_bf16(a0[mf][kk], bfr[nf][kk], acc[mf][nf], 0, 0, 0);
    __builtin_amdgcn_s_setprio(0);
    __builtin_amdgcn_s_barrier();
    // ---- phase 1: read a1; stage B.h0(t+2); MFMA (m0,n23)
#pragma unroll
    for (int mf = 0; mf < 4; ++mf) {
      const int rowi = wrow * 128 + 64 + mf * 16 + lo;
#pragma unroll
      for (int kk = 0; kk < 2; ++kk)
        a1[mf][kk] = *(const bf16x8*)&Ab_[rowi * 64 + ((kk * 32 + g * 8) ^ swz)];
    }
    if (t + 2 < NT)
      ST2(pB0, pB1, sm + (t & 1) * 32768 + 16384);
    __builtin_amdgcn_s_barrier();
    __builtin_amdgcn_s_setprio(1);
#pragma unroll
    for (int mf = 0; mf < 4; ++mf)
#pragma unroll
      for (int nf = 2; nf < 4; ++nf)
#pragma unroll
        for (int kk = 0; kk < 2; ++kk)
          acc[mf][nf] = __builtin_amdgcn_mfma_f32_16x16x32_bf16(a0[mf][kk], bfr[nf][kk], acc[mf][nf], 0, 0, 0);
    __builtin_amdgcn_s_setprio(0);
    __builtin_amdgcn_s_barrier();
    // ---- phase 2: stage B.h1(t+2); MFMA (m1,n01)
    if (t + 2 < NT)
      ST2(pB2, pB3, sm + (t & 1) * 32768 + 16384 + 8192);
    __builtin_amdgcn_s_barrier();
    __builtin_amdgcn_s_setprio(1);
#pragma unroll
    for (int mf = 0; mf < 4; ++mf)
#pragma unroll
      for (int nf = 0; nf < 2; ++nf)
#pragma unroll
        for (int kk = 0; kk < 2; ++kk)
          acc[4 + mf][nf] = __builtin_amdgcn_mfma_f32_16x16x32_bf16(a1[mf][kk], bfr[nf][kk], acc[4 + mf][nf], 0, 0, 0);
    __builtin_amdgcn_s_setprio(0);
    __builtin_amdgcn_s_barrier();
    // ---- phase 3: stage A.h0(t+2); MFMA (m1,n23); counted vmcnt (0 at tail)
    if (t + 2 < NT)
      ST2(pA0, pA1, sm + (t & 1) * 32768);
    __builtin_amdgcn_s_barrier();
    __builtin_amdgcn_s_setprio(1);
#pragma unroll
    for (int mf = 0; mf < 4; ++mf)
#pragma unroll
      for (int nf = 2; nf < 4; ++nf)
#pragma unroll
        for (int kk = 0; kk < 2; ++kk)
          acc[4 + mf][nf] = __builtin_amdgcn_mfma_f32_16x16x32_bf16(a1[mf][kk], bfr[nf][kk], acc[4 + mf][nf], 0, 0, 0);
    __builtin_amdgcn_s_setprio(0);
    if (t + 2 < NT) asm volatile("s_waitcnt vmcnt(6)" ::: "memory");
    else            asm volatile("s_waitcnt vmcnt(0)" ::: "memory");
    __builtin_amdgcn_s_barrier();
  }

  if (MODE == 1) {
    // register-paired GEGLU: acc[mi][2s]=h1, acc[mi][2s+1]=h2, same out col.
    const int obase = bn >> 1;
#pragma unroll
    for (int mi = 0; mi < 8; ++mi) {
#pragma unroll
      for (int sub = 0; sub < 2; ++sub) {
        const int col = obase + wcol * 32 + sub * 16 + lo;
        const float b1 = bias[col];
        const float b2 = bias[4096 + col];
#pragma unroll
        for (int rr = 0; rr < 4; ++rr) {
          const int rowi = wrow * 128 + mi * 16 + g * 4 + rr;
          const float h1 = acc[mi][sub * 2][rr] + b1;
          const float h2 = acc[mi][sub * 2 + 1][rr] + b2;
          const float ge = 0.5f * h2 * (1.0f + erff(h2 * 0.70710678118f));
          outB[(size_t)(bm + rowi) * 4096 + col] = f2bf(h1 * ge);
        }
      }
    }
    return;
  }

#pragma unroll
  for (int mi = 0; mi < 8; ++mi) {
#pragma unroll
    for (int ni = 0; ni < 4; ++ni) {
      const int col = bn + wcol * 64 + ni * 16 + lo;
      const float bb = bias ? bias[col] : 0.0f;
      const int row0 = bm + wrow * 128 + mi * 16 + g * 4;
#pragma unroll
      for (int rr = 0; rr < 4; ++rr) {
        const size_t off = (size_t)(row0 + rr) * N + col;
        float v = acc[mi][ni][rr] * oscale + bb;
        if (resid) v += resid[off];
        if (outF) outF[off] = v;
        else outB[off] = f2bf(v);
      }
    }
  }
}

// ---------------- fused flash attention v6: QK-ahead pipeline, unroll-2 loop
// (static buffers per parity, no state copies), running staging pointers,
// MFMA row-sum lsum + defer-max (THR=8, base-2).
#define ABODY(TT, KST, KRD, VST, VRD, SCur, SNxt)                                  \
  {                                                                                \
    if ((TT) + 2 < ntile) {                                                        \
      gld16(kp0, &KST[tid * 8]);                                                   \
      gld16(kp1, &KST[2048 + tid * 8]);                                            \
      kp0 += kadv; kp1 += kadv;                                                    \
    }                                                                              \
    if ((TT) + 1 < ntile) {                                                        \
      gld16(vp0, &VST[tid * 8]);                                                   \
      gld16(vp1, &VST[2048 + tid * 8]);                                            \
      vp0 += 64; vp1 += 64;                                                        \
    }                                                                              \
    if ((TT) + 2 < ntile)      asm volatile("s_waitcnt vmcnt(4)" ::: "memory");    \
    else if ((TT) + 1 < ntile) asm volatile("s_waitcnt vmcnt(2)" ::: "memory");    \
    else                       asm volatile("s_waitcnt vmcnt(0)" ::: "memory");    \
    __builtin_amdgcn_s_barrier();                                                  \
    if ((TT) + 1 < ntile) {                                                        \
      _Pragma("unroll")                                                            \
      for (int c = 0; c < 4; ++c) {                                                \
        f32x4 zz = {};                                                             \
        SNxt[c] = zz;                                                              \
        _Pragma("unroll")                                                          \
        for (int kk = 0; kk < 2; ++kk) {                                           \
          bf16x8 kf = *(const bf16x8*)&KRD[(c * 16 + lo) * 64 +                    \
                                           ((kk * 32 + g * 8) ^ ((lo & 7) << 3))]; \
          SNxt[c] = __builtin_amdgcn_mfma_f32_16x16x32_bf16(kf, qf[kk], SNxt[c], 0, 0, 0); \
        }                                                                          \
      }                                                                            \
    }                                                                              \
    float mx = fmaxf(fmaxf(fmaxf(SCur[0][0], SCur[0][1]), fmaxf(SCur[0][2], SCur[0][3])),  \
                     fmaxf(fmaxf(SCur[1][0], SCur[1][1]), fmaxf(SCur[1][2], SCur[1][3]))); \
    mx = fmaxf(mx, fmaxf(fmaxf(fmaxf(SCur[2][0], SCur[2][1]), fmaxf(SCur[2][2], SCur[2][3])),  \
                         fmaxf(fmaxf(SCur[3][0], SCur[3][1]), fmaxf(SCur[3][2], SCur[3][3])))); \
    mx = fmaxf(mx, __shfl_xor(mx, 16));                                            \
    mx = fmaxf(mx, __shfl_xor(mx, 32));                                            \
    if (!__all(mx <= m + 8.0f)) {                                                  \
      const float mn = fmaxf(m, mx);                                               \
      const float al = exp2f(m - mn);                                              \
      m = mn;                                                                      \
      f32x4 arv;                                                                   \
      _Pragma("unroll")                                                            \
      for (int rr = 0; rr < 4; ++rr) arv[rr] = __shfl(al, 20 * g + rr);            \
      _Pragma("unroll")                                                            \
      for (int dn = 0; dn < 4; ++dn) oa[dn] *= arv;                                \
      lrow *= arv;                                                                 \
    }                                                                              \
    _Pragma("unroll")                                                              \
    for (int c = 0; c < 4; ++c)                                                    \
      _Pragma("unroll")                                                            \
      for (int rr = 0; rr < 4; ++rr)                                               \
        SCur[c][rr] = exp2f(SCur[c][rr] - m);                                      \
    union { uint32_t u[4]; bf16x8 v; } af[2];                                      \
    _Pragma("unroll")                                                              \
    for (int ks = 0; ks < 2; ++ks) {                                               \
      af[ks].u[0] = cvtpk(SCur[2 * ks][0], SCur[2 * ks][1]);                       \
      af[ks].u[1] = cvtpk(SCur[2 * ks][2], SCur[2 * ks][3]);                       \
      af[ks].u[2] = cvtpk(SCur[2 * ks + 1][0], SCur[2 * ks + 1][1]);               \
      af[ks].u[3] = cvtpk(SCur[2 * ks + 1][2], SCur[2 * ks + 1][3]);               \
    }                                                                              \
    lrow = __builtin_amdgcn_mfma_f32_16x16x32_bf16(af[0].v, onesc.v, lrow, 0, 0, 0); \
    lrow = __builtin_amdgcn_mfma_f32_16x16x32_bf16(af[1].v, onesc.v, lrow, 0, 0, 0); \
    _Pragma("unroll")                                                              \
    for (int dn = 0; dn < 4; ++dn)                                                 \
      _Pragma("unroll")                                                            \
      for (int ks = 0; ks < 2; ++ks) {                                             \
        bf16x8 vf = *(const bf16x8*)&VRD[(dn * 16 + lo) * 64 +                     \
                                         ((ks * 32 + g * 8) ^ ((lo & 7) << 3))];   \
        oa[dn] = __builtin_amdgcn_mfma_f32_16x16x32_bf16(af[ks].v, vf, oa[dn], 0, 0, 0); \
      }                                                                            \
    asm volatile("s_waitcnt lgkmcnt(0)" ::: "memory");                             \
    __builtin_amdgcn_s_barrier();                                                  \
  }

__global__ __launch_bounds__(256, 4)
void attn_fwd(const u16* __restrict__ Q, int ldq, const u16* __restrict__ K, int ldk,
              const u16* __restrict__ Vt, u16* __restrict__ O, int T, int S) {
  __shared__ __align__(16) u16 Kl[2][4096];
  __shared__ __align__(16) u16 Vl[2][4096];
  const int tid = threadIdx.x, w = tid >> 6, l = tid & 63, lo = l & 15, g = l >> 4;
  const int nwg = gridDim.x * gridDim.y;
  const int n = blockIdx.y * gridDim.x + blockIdx.x;
  const int sid = (n & 7) * (nwg >> 3) + (n >> 3);
  const int qt = sid % gridDim.x, bh = sid / gridDim.x;
  const int b = bh >> 4, h = bh & 15, hc = h * 64;
  const int q0 = qt * 64 + w * 16;
  const size_t qrow = (size_t)b * T + q0;
  const size_t krow0 = (size_t)b * S;
  const size_t vrow0 = (size_t)bh * 64;

  bf16x8 qf[2];
#pragma unroll
  for (int kk = 0; kk < 2; ++kk)
    qf[kk] = *(const bf16x8*)&Q[(qrow + lo) * ldq + hc + kk * 32 + g * 8];

  // all-ones bf16 fragment for MFMA row-sum
  union { u16 u[8]; bf16x8 v; } onesc;
#pragma unroll
  for (int j = 0; j < 8; ++j) onesc.u[j] = 0x3F80;

  f32x4 oa[4] = {};
  f32x4 lrow = {};
  float m = -1e30f;

  const int srow = tid >> 3;
  const int scol = (((tid & 7) ^ (srow & 7)) << 3);
  const int ntile = S >> 6;
  const size_t kadv = (size_t)64 * ldk;

  // running staging pointers: next K tile = 2, next V tile = 1 (after prologue)
  const u16* kp0 = K + (krow0 + 128 + srow) * ldk + hc + scol;
  const u16* kp1 = K + (krow0 + 160 + srow) * ldk + hc + scol;
  const u16* vp0 = Vt + (vrow0 + srow) * S + 64 + scol;
  const u16* vp1 = Vt + (vrow0 + 32 + srow) * S + 64 + scol;

  // prologue: K(0)->Kl[0], K(1)->Kl[1], V(0)->Vl[0]; then QK(0)->sC
#pragma unroll
  for (int c = 0; c < 2; ++c)
    gld16(K + (krow0 + c * 32 + srow) * ldk + hc + scol, &Kl[0][c * 2048 + tid * 8]);
#pragma unroll
  for (int c = 0; c < 2; ++c)
    gld16(K + (krow0 + 64 + c * 32 + srow) * ldk + hc + scol, &Kl[1][c * 2048 + tid * 8]);
#pragma unroll
  for (int c = 0; c < 2; ++c)
    gld16(Vt + (vrow0 + c * 32 + srow) * S + scol, &Vl[0][c * 2048 + tid * 8]);
  asm volatile("s_waitcnt vmcnt(0)" ::: "memory");
  __builtin_amdgcn_s_barrier();

  f32x4 sC[4] = {}, sN[4] = {};
#pragma unroll
  for (int c = 0; c < 4; ++c)
#pragma unroll
    for (int kk = 0; kk < 2; ++kk) {
      bf16x8 kf = *(const bf16x8*)&Kl[0][(c * 16 + lo) * 64 +
                                        ((kk * 32 + g * 8) ^ ((lo & 7) << 3))];
      sC[c] = __builtin_amdgcn_mfma_f32_16x16x32_bf16(kf, qf[kk], sC[c], 0, 0, 0);
    }
  asm volatile("s_waitcnt lgkmcnt(0)" ::: "memory");
  __builtin_amdgcn_s_barrier();

  for (int t0 = 0; t0 < ntile; t0 += 2) {
    ABODY(t0,     Kl[0], Kl[1], Vl[1], Vl[0], sC, sN)
    ABODY(t0 + 1, Kl[1], Kl[0], Vl[0], Vl[1], sN, sC)
  }

#pragma unroll
  for (int dn = 0; dn < 4; ++dn)
#pragma unroll
    for (int rr = 0; rr < 4; ++rr)
      O[(qrow + g * 4 + rr) * 1024 + hc + dn * 16 + lo] = f2bf(oa[dn][rr] / lrow[rr]);
}

extern "C" void kernel_launch(void* const* d_in, const int* in_sizes, int n_in,
                              void* d_out, int out_size, void* d_ws, size_t ws_size,
                              hipStream_t stream) {
  const float* x      = (const float*)d_in[0];
  const float* enc    = (const float*)d_in[1];
  const float* ln1_w  = (const float*)d_in[2];
  const float* ln1_b  = (const float*)d_in[3];
  const float* a1_wq  = (const float*)d_in[4];
  const float* a1_wk  = (const float*)d_in[5];
  const float* a1_wv  = (const float*)d_in[6];
  const float* a1_wo  = (const float*)d_in[7];
  const float* a1_bo  = (const float*)d_in[8];
  const float* ln2_w  = (const float*)d_in[9];
  const float* ln2_b  = (const float*)d_in[10];
  const float* a2_wq  = (const float*)d_in[11];
  const float* a2_wk  = (const float*)d_in[12];
  const float* a2_wv  = (const float*)d_in[13];
  const float* a2_wo  = (const float*)d_in[14];
  const float* a2_bo  = (const float*)d_in[15];
  const float* ln3_w  = (const float*)d_in[16];
  const float* ln3_b  = (const float*)d_in[17];
  const float* ff_w1  = (const float*)d_in[18];
  const float* ff_b1  = (const float*)d_in[19];
  const float* ff_w2  = (const float*)d_in[20];
  const float* ff_b2  = (const float*)d_in[21];

  char* ws = (char*)d_ws;
  const size_t MB = 1u << 20;
  u16* wqkv1t = (u16*)(ws + 0 * MB);              // 3072x1024 = 6 MB
  u16* wo1t   = (u16*)(ws + 6 * MB);
  u16* wq2t   = (u16*)(ws + 8 * MB);
  u16* wo2t   = (u16*)(ws + 10 * MB);
  u16* wkv2t  = (u16*)(ws + 12 * MB);             // 2048x64 = 256 KB
  u16* encb   = (u16*)(ws + 12 * MB + 512 * 1024);
  u16* w1t    = (u16*)(ws + 13 * MB);             // 16 MB (geglu-paired)
  u16* w2t    = (u16*)(ws + 29 * MB);             // 8 MB
  float* x2   = (float*)(ws + 37 * MB);           // 16 MB (live from wo2 on)
  u16* Vt1    = (u16*)(ws + 37 * MB);             // 8 MB (dead before wo2)
  u16* Vt2    = (u16*)(ws + 45 * MB);             // 2 MB (dead before wo2)
  u16* KVb    = (u16*)(ws + 47 * MB);             // 1024x2048 = 4 MB
  u16* hbuf   = (u16*)(ws + 53 * MB);             // 8 MB
  u16* qkv    = (u16*)(ws + 61 * MB);             // 24 MB
  u16* Qb     = (u16*)(ws + 61 * MB);             // cross-attn reuse
  u16* Ab     = (u16*)(ws + 85 * MB);             // 8 MB
  float* x1   = (float*)(ws + 93 * MB);           // 16 MB -> 109
  u16* gq     = (u16*)(ws + 61 * MB);             // 4096x4096 = 32 MB (reuses qkv/Ab)

  const float SCL = 0.125f * 1.44269504f;
  const dim3 tb(32, 8);
  {
    WB wb;
    wb.src[0] = a1_wq; wb.dst[0] = wqkv1t;               wb.scale[0] = SCL;
    wb.src[1] = a1_wk; wb.dst[1] = wqkv1t + 1024 * 1024; wb.scale[1] = 1.0f;
    wb.src[2] = a1_wv; wb.dst[2] = wqkv1t + 2048 * 1024; wb.scale[2] = 1.0f;
    wb.src[3] = a1_wo; wb.dst[3] = wo1t;                 wb.scale[3] = 1.0f;
    wb.src[4] = a2_wq; wb.dst[4] = wq2t;                 wb.scale[4] = SCL;
    wb.src[5] = a2_wo; wb.dst[5] = wo2t;                 wb.scale[5] = 1.0f;
    wconv_b<<<dim3(32, 32, 6), tb, 0, stream>>>(wb, 1024, 1024);
    WB wb2;
    wb2.src[0] = a2_wk; wb2.dst[0] = wkv2t;             wb2.scale[0] = 1.0f;
    wb2.src[1] = a2_wv; wb2.dst[1] = wkv2t + 64 * 1024; wb2.scale[1] = 1.0f;
    wb2.src[2] = a2_wk; wb2.dst[2] = wkv2t;             wb2.scale[2] = 1.0f;
    wb2.src[3] = a2_wk; wb2.dst[3] = wkv2t;             wb2.scale[3] = 1.0f;
    wb2.src[4] = a2_wk; wb2.dst[4] = wkv2t;             wb2.scale[4] = 1.0f;
    wb2.src[5] = a2_wk; wb2.dst[5] = wkv2t;             wb2.scale[5] = 1.0f;
    wconv_b<<<dim3(32, 2, 2), tb, 0, stream>>>(wb2, 64, 1024);
  }
  wconv_g<<<dim3(256, 32), tb, 0, stream>>>(ff_w1, w1t);
  wconv_t<<<dim3(32, 128), tb, 0, stream>>>(ff_w2, w2t, 4096, 1024);
  cvt_bf<<<256, 256, 0, stream>>>(enc, encb, 2 * 512 * 64);

  // ---- self-attention sub-block
  ln_fwd<<<4096, 256, 0, stream>>>(x, ln1_w, ln1_b, hbuf);
  gemm256<0><<<dim3(16, 12), 512, 0, stream>>>(hbuf, 1024, wqkv1t, 4096, 3072, 1024, nullptr, nullptr, 1.0f, nullptr, qkv);
  vtrans<<<dim3(32, 32), 256, 0, stream>>>(qkv, 3072, 2048, Vt1, 2048);
  attn_fwd<<<dim3(32, 32), 256, 0, stream>>>(qkv, 3072, qkv + 1024, 3072, Vt1, Ab, 2048, 2048);
  gemm_bf16<64><<<dim3(32, 16), 256, 0, stream>>>(Ab, 1024, wo1t, 4096, 1024, 1024, a1_bo, x, 1.0f, x1, nullptr);

  // ---- cross-attention sub-block
  ln_fwd<<<4096, 256, 0, stream>>>(x1, ln2_w, ln2_b, hbuf);
  gemm_bf16<64><<<dim3(32, 16), 256, 0, stream>>>(hbuf, 1024, wq2t, 4096, 1024, 1024, nullptr, nullptr, 1.0f, nullptr, Qb);
  gemm_bf16<64><<<dim3(8, 32), 256, 0, stream>>>(encb, 64, wkv2t, 1024, 2048, 64, nullptr, nullptr, 1.0f, nullptr, KVb);
  vtrans<<<dim3(8, 32), 256, 0, stream>>>(KVb + 1024, 2048, 0, Vt2, 512);
  attn_fwd<<<dim3(32, 32), 256, 0, stream>>>(Qb, 1024, KVb, 2048, Vt2, Ab, 2048, 512);
  gemm_bf16<64><<<dim3(32, 16), 256, 0, stream>>>(Ab, 1024, wo2t, 4096, 1024, 1024, a2_bo, x1, 1.0f, x2, nullptr);

  // ---- GEGLU feed-forward sub-block (geglu fused into FF1 epilogue)
  ln_fwd<<<4096, 256, 0, stream>>>(x2, ln3_w, ln3_b, hbuf);
  gemm256<1><<<dim3(16, 32), 512, 0, stream>>>(hbuf, 1024, w1t, 4096, 8192, 1024, ff_b1, nullptr, 1.0f, nullptr, gq);
  gemm_bf16<64><<<dim3(32, 16), 256, 0, stream>>>(gq, 4096, w2t, 4096, 1024, 4096, ff_b2, x2, 1.0f, (float*)d_out, nullptr);
}